// Round 1
// baseline (1416.808 us; speedup 1.0000x reference)
//
#include <hip/hip_runtime.h>

typedef __bf16 bf16x8 __attribute__((ext_vector_type(8)));
typedef float f32x4 __attribute__((ext_vector_type(4)));
typedef unsigned short u16;
typedef u16 u16x8 __attribute__((ext_vector_type(8)));
typedef u16 u16x4 __attribute__((ext_vector_type(4)));

#define B_ 2
#define S_ 2048
#define D_ 4096
#define H_ 32
#define HD_ 128
#define SM_SCALE 0.08838834764831845f  // 1/sqrt(128)

__device__ __forceinline__ u16 f2bf(float f) {
  __bf16 h = (__bf16)f;
  return __builtin_bit_cast(unsigned short, h);
}
__device__ __forceinline__ float bf2f(u16 u) {
  return (float)__builtin_bit_cast(__bf16, u);
}

// async global->LDS, 16B per lane. LDS dest must be wave-uniform-base + lane*16.
#define GLD_TO_LDS16(gsrc, ldst)                                                     \
  __builtin_amdgcn_global_load_lds((__attribute__((address_space(1))) void*)(gsrc),  \
                                   (__attribute__((address_space(3))) void*)(ldst),  \
                                   16, 0, 0)

// ---------------- fp32 -> bf16 conversion ----------------
__global__ __launch_bounds__(256) void cvt_kernel(const float* __restrict__ src,
                                                  u16* __restrict__ dst, int n4) {
  int i = blockIdx.x * blockDim.x + threadIdx.x;
  int stride = gridDim.x * blockDim.x;
  for (; i < n4; i += stride) {
    float4 v = reinterpret_cast<const float4*>(src)[i];
    u16x4 o;
    o[0] = f2bf(v.x); o[1] = f2bf(v.y); o[2] = f2bf(v.z); o[3] = f2bf(v.w);
    reinterpret_cast<u16x4*>(dst)[i] = o;
  }
}

// ---------------- RoPE (in place on bf16 (B*S, D) tensor) ----------------
__global__ __launch_bounds__(256) void rope_kernel(u16* __restrict__ T,
                                                   const float* __restrict__ fc,
                                                   const float* __restrict__ fs) {
  const int n = B_ * S_ * D_ / 2;  // pairs
  int i = blockIdx.x * blockDim.x + threadIdx.x;
  int stride = gridDim.x * blockDim.x;
  unsigned int* Tp = reinterpret_cast<unsigned int*>(T);
  for (; i < n; i += stride) {
    int row = i >> 11;       // D/2 = 2048 pairs per row
    int pr = i & 2047;       // pair-in-row = h*64 + p
    int s = row & (S_ - 1);
    int p = pr & 63;
    float c = fc[(s << 6) + p];
    float sn = fs[(s << 6) + p];
    unsigned int u = Tp[i];  // pair offset in uints == i
    float xr = bf2f((u16)(u & 0xffff));
    float xi = bf2f((u16)(u >> 16));
    float orr = xr * c - xi * sn;
    float oii = xr * sn + xi * c;
    Tp[i] = (unsigned int)f2bf(orr) | ((unsigned int)f2bf(oii) << 16);
  }
}

// ---------------- GEMM: C[M,N] = A[M,K] * B[N,K]^T  (bf16 in, fp32 acc) ----------------
// 128x128 tile, BK=64, 4 waves (2x2), each wave 64x64 via 4x4 16x16x32 MFMA frags.
// LDS linear (global_load_lds) with chunk-XOR swizzle applied at the GLOBAL source
// and on the ds_read index (rule #21: both sides or neither).
template <typename OutT>
__global__ __launch_bounds__(256) void gemm_bt_kernel(const u16* __restrict__ A,
                                                      const u16* __restrict__ Bw,
                                                      OutT* __restrict__ C,
                                                      int M, int N, int K) {
  __shared__ u16 As[128 * 64];
  __shared__ u16 Bs[128 * 64];
  const int tid = threadIdx.x;
  const int lane = tid & 63;
  const int w = tid >> 6;
  const int wr = w >> 1, wc = w & 1;
  const int nbx = N >> 7;
  const int nwg = (M >> 7) * nbx;
  int wg = blockIdx.x;
  if ((nwg & 7) == 0) wg = (wg & 7) * (nwg >> 3) + (wg >> 3);  // XCD swizzle (bijective)
  const int tr = wg / nbx, tc = wg % nbx;

  f32x4 acc[4][4] = {};

  const int ktn = K >> 6;
  for (int kt = 0; kt < ktn; ++kt) {
    const int k0 = kt << 6;
#pragma unroll
    for (int it = 0; it < 4; ++it) {
      int ff = it * 256 + tid;
      int row = ff >> 3, cc = ff & 7;
      int scc = cc ^ (row & 7);  // pre-swizzled source column-chunk
      GLD_TO_LDS16(A + (size_t)(tr * 128 + row) * K + k0 + scc * 8, &As[ff << 3]);
      GLD_TO_LDS16(Bw + (size_t)(tc * 128 + row) * K + k0 + scc * 8, &Bs[ff << 3]);
    }
    __syncthreads();
#pragma unroll
    for (int kk = 0; kk < 2; ++kk) {
      bf16x8 af[4], bfr[4];
#pragma unroll
      for (int m = 0; m < 4; ++m) {
        int row = wr * 64 + m * 16 + (lane & 15);
        int kc = kk * 4 + (lane >> 4);
        af[m] = *reinterpret_cast<const bf16x8*>(&As[(row << 6) + ((kc ^ (row & 7)) << 3)]);
      }
#pragma unroll
      for (int n = 0; n < 4; ++n) {
        int row = wc * 64 + n * 16 + (lane & 15);
        int kc = kk * 4 + (lane >> 4);
        bfr[n] = *reinterpret_cast<const bf16x8*>(&Bs[(row << 6) + ((kc ^ (row & 7)) << 3)]);
      }
#pragma unroll
      for (int m = 0; m < 4; ++m)
#pragma unroll
        for (int n = 0; n < 4; ++n)
          acc[m][n] = __builtin_amdgcn_mfma_f32_16x16x32_bf16(af[m], bfr[n], acc[m][n], 0, 0, 0);
    }
    __syncthreads();
  }
  const int r0 = tr * 128 + wr * 64;
  const int c0 = tc * 128 + wc * 64;
#pragma unroll
  for (int m = 0; m < 4; ++m)
#pragma unroll
    for (int n = 0; n < 4; ++n)
#pragma unroll
      for (int r = 0; r < 4; ++r) {
        int row = r0 + m * 16 + ((lane >> 4) << 2) + r;
        int col = c0 + n * 16 + (lane & 15);
        float v = acc[m][n][r];
        if constexpr (__is_same(OutT, float)) {
          C[(size_t)row * N + col] = v;
        } else {
          C[(size_t)row * N + col] = f2bf(v);
        }
      }
}

// ---------------- Flash attention (causal), bf16 QKV -> bf16 O ----------------
// grid: B*H*(S/128) = 1024 blocks; 4 waves, each owns 32 q-rows; KV tiles of 64.
__global__ __launch_bounds__(256) void attn_kernel(const u16* __restrict__ Q,
                                                   const u16* __restrict__ K,
                                                   const u16* __restrict__ V,
                                                   u16* __restrict__ O) {
  __shared__ u16 Ks[64 * 128];   // [kv][d], chunk-XOR swizzled
  __shared__ u16 Vt[128 * 64];   // [d][kv], chunk-XOR swizzled
  __shared__ u16 Ps[4][32 * 64]; // per-wave P, [q][kv], chunk-XOR swizzled

  const int qt = blockIdx.x & 15;
  const int bh = blockIdx.x >> 4;
  const int b = bh >> 5, h = bh & 31;
  const int q0 = qt << 7;
  const int tid = threadIdx.x, lane = tid & 63, w = tid >> 6;

  // Q fragments straight from global (A-operand layout: row=lane&15, 8 contiguous k)
  bf16x8 qf[2][4];
#pragma unroll
  for (int m = 0; m < 2; ++m)
#pragma unroll
    for (int kk = 0; kk < 4; ++kk) {
      int row = q0 + w * 32 + m * 16 + (lane & 15);
      int k = kk * 32 + ((lane >> 4) << 3);
      qf[m][kk] = *reinterpret_cast<const bf16x8*>(Q + (size_t)(b * S_ + row) * D_ + h * HD_ + k);
    }

  f32x4 oacc[2][8] = {};
  float mrun[2][4], lrun[2][4];
#pragma unroll
  for (int m = 0; m < 2; ++m)
#pragma unroll
    for (int r = 0; r < 4; ++r) { mrun[m][r] = -__builtin_inff(); lrun[m][r] = 0.f; }

  const int ntiles = 2 * qt + 2;  // covers kv <= q0+127
  for (int t = 0; t < ntiles; ++t) {
    const int kv0 = t << 6;
    // stage K tile (64x128) via global_load_lds, source pre-swizzled
#pragma unroll
    for (int it = 0; it < 4; ++it) {
      int ff = it * 256 + tid;
      int row = ff >> 4, cc = ff & 15;
      int scc = cc ^ (row & 7);
      GLD_TO_LDS16(K + (size_t)(b * S_ + kv0 + row) * D_ + h * HD_ + scc * 8, &Ks[ff << 3]);
    }
    // stage V transposed via registers (lane==kv -> conflict-free ds writes)
#pragma unroll
    for (int it = 0; it < 4; ++it) {
      int ff = it * 256 + tid;
      int r = ff & 63, dc = ff >> 6;
      u16x8 v = *reinterpret_cast<const u16x8*>(V + (size_t)(b * S_ + kv0 + r) * D_ + h * HD_ + dc * 8);
#pragma unroll
      for (int j = 0; j < 8; ++j) {
        int d = dc * 8 + j;
        Vt[(d << 6) + (((r >> 3) ^ (d & 7)) << 3) + (r & 7)] = v[j];
      }
    }
    __syncthreads();

    if (kv0 <= q0 + w * 32 + 31) {  // wave-uniform causal skip
      // S = Q K^T (fp32 frags)
      f32x4 s[2][4] = {};
#pragma unroll
      for (int kk = 0; kk < 4; ++kk) {
        bf16x8 kf[4];
#pragma unroll
        for (int n = 0; n < 4; ++n) {
          int row = n * 16 + (lane & 15);
          int kc = kk * 4 + (lane >> 4);
          kf[n] = *reinterpret_cast<const bf16x8*>(&Ks[(row << 7) + ((kc ^ (row & 7)) << 3)]);
        }
#pragma unroll
        for (int m = 0; m < 2; ++m)
#pragma unroll
          for (int n = 0; n < 4; ++n)
            s[m][n] = __builtin_amdgcn_mfma_f32_16x16x32_bf16(qf[m][kk], kf[n], s[m][n], 0, 0, 0);
      }
      // causal mask on diagonal-crossing tiles
      if (kv0 + 63 > q0 + w * 32) {
#pragma unroll
        for (int m = 0; m < 2; ++m)
#pragma unroll
          for (int n = 0; n < 4; ++n)
#pragma unroll
            for (int r = 0; r < 4; ++r) {
              int rowg = q0 + w * 32 + m * 16 + ((lane >> 4) << 2) + r;
              int colg = kv0 + n * 16 + (lane & 15);
              if (colg > rowg) s[m][n][r] = -1e30f;
            }
      }
      // online softmax (track raw max; fold scale into exp arg)
#pragma unroll
      for (int m = 0; m < 2; ++m) {
        float psc[4];
#pragma unroll
        for (int r = 0; r < 4; ++r) {
          float vmax = fmaxf(fmaxf(s[m][0][r], s[m][1][r]), fmaxf(s[m][2][r], s[m][3][r]));
          vmax = fmaxf(vmax, __shfl_xor(vmax, 1));
          vmax = fmaxf(vmax, __shfl_xor(vmax, 2));
          vmax = fmaxf(vmax, __shfl_xor(vmax, 4));
          vmax = fmaxf(vmax, __shfl_xor(vmax, 8));
          float mnew = fmaxf(mrun[m][r], vmax);
          float sc = __expf((mrun[m][r] - mnew) * SM_SCALE);
          mrun[m][r] = mnew;
          float psum = 0.f;
#pragma unroll
          for (int n = 0; n < 4; ++n) {
            float p = __expf((s[m][n][r] - mnew) * SM_SCALE);
            s[m][n][r] = p;
            psum += p;
          }
          psum += __shfl_xor(psum, 1);
          psum += __shfl_xor(psum, 2);
          psum += __shfl_xor(psum, 4);
          psum += __shfl_xor(psum, 8);
          lrun[m][r] = lrun[m][r] * sc + psum;
          psc[r] = sc;
        }
#pragma unroll
        for (int n = 0; n < 8; ++n)
#pragma unroll
          for (int r = 0; r < 4; ++r) oacc[m][n][r] *= psc[r];
      }
      // P (bf16) -> per-wave LDS (C/D layout -> A layout through LDS)
      u16* P = Ps[w];
#pragma unroll
      for (int m = 0; m < 2; ++m)
#pragma unroll
        for (int n = 0; n < 4; ++n)
#pragma unroll
          for (int r = 0; r < 4; ++r) {
            int prow = m * 16 + ((lane >> 4) << 2) + r;
            int pcol = n * 16 + (lane & 15);
            P[(prow << 6) + (((pcol >> 3) ^ (prow & 7)) << 3) + (pcol & 7)] = f2bf(s[m][n][r]);
          }
      // O += P V
#pragma unroll
      for (int kk2 = 0; kk2 < 2; ++kk2) {
        bf16x8 pa[2];
#pragma unroll
        for (int m = 0; m < 2; ++m) {
          int prow = m * 16 + (lane & 15);
          int kc = kk2 * 4 + (lane >> 4);
          pa[m] = *reinterpret_cast<const bf16x8*>(&P[(prow << 6) + ((kc ^ (prow & 7)) << 3)]);
        }
#pragma unroll
        for (int n = 0; n < 8; ++n) {
          int vrow = n * 16 + (lane & 15);
          int kc = kk2 * 4 + (lane >> 4);
          bf16x8 vf = *reinterpret_cast<const bf16x8*>(&Vt[(vrow << 6) + ((kc ^ (vrow & 7)) << 3)]);
#pragma unroll
          for (int m = 0; m < 2; ++m)
            oacc[m][n] = __builtin_amdgcn_mfma_f32_16x16x32_bf16(pa[m], vf, oacc[m][n], 0, 0, 0);
        }
      }
    }
    __syncthreads();
  }
  // epilogue: O / l -> bf16
#pragma unroll
  for (int m = 0; m < 2; ++m)
#pragma unroll
    for (int n = 0; n < 8; ++n)
#pragma unroll
      for (int r = 0; r < 4; ++r) {
        int rowg = q0 + w * 32 + m * 16 + ((lane >> 4) << 2) + r;
        int colg = n * 16 + (lane & 15);
        float v = oacc[m][n][r] / lrun[m][r];
        O[(size_t)(b * S_ + rowg) * D_ + h * HD_ + colg] = f2bf(v);
      }
}

// ---------------- launcher ----------------
extern "C" void kernel_launch(void* const* d_in, const int* in_sizes, int n_in,
                              void* d_out, int out_size, void* d_ws, size_t ws_size,
                              hipStream_t stream) {
  const float* x = (const float*)d_in[0];
  const float* wq = (const float*)d_in[1];
  const float* wk = (const float*)d_in[2];
  const float* wv = (const float*)d_in[3];
  const float* wo = (const float*)d_in[4];
  const float* fc = (const float*)d_in[5];
  const float* fs = (const float*)d_in[6];
  float* out = (float*)d_out;

  const size_t SLOT = (size_t)B_ * S_ * D_;  // 16,777,216 elements
  u16* ws = (u16*)d_ws;
  u16* wqb = ws + 0 * SLOT;
  u16* wkb = ws + 1 * SLOT;
  u16* wvb = ws + 2 * SLOT;
  u16* wob = ws + 3 * SLOT;
  u16* xb  = ws + 4 * SLOT;  // reused as attention output O after QKV GEMMs
  u16* Qb  = ws + 5 * SLOT;
  u16* Kb  = ws + 6 * SLOT;
  u16* Vb  = ws + 7 * SLOT;
  u16* Ob  = xb;

  const int n4 = (int)(SLOT / 4);
  cvt_kernel<<<2048, 256, 0, stream>>>(x, xb, n4);
  cvt_kernel<<<2048, 256, 0, stream>>>(wq, wqb, n4);
  cvt_kernel<<<2048, 256, 0, stream>>>(wk, wkb, n4);
  cvt_kernel<<<2048, 256, 0, stream>>>(wv, wvb, n4);
  cvt_kernel<<<2048, 256, 0, stream>>>(wo, wob, n4);

  gemm_bt_kernel<u16><<<1024, 256, 0, stream>>>(xb, wqb, Qb, B_ * S_, D_, D_);
  gemm_bt_kernel<u16><<<1024, 256, 0, stream>>>(xb, wkb, Kb, B_ * S_, D_, D_);
  gemm_bt_kernel<u16><<<1024, 256, 0, stream>>>(xb, wvb, Vb, B_ * S_, D_, D_);

  rope_kernel<<<2048, 256, 0, stream>>>(Qb, fc, fs);
  rope_kernel<<<2048, 256, 0, stream>>>(Kb, fc, fs);

  attn_kernel<<<1024, 256, 0, stream>>>(Qb, Kb, Vb, Ob);

  gemm_bt_kernel<float><<<1024, 256, 0, stream>>>(Ob, wob, out, B_ * S_, D_, D_);
}

// Round 2
// 1155.282 us; speedup vs baseline: 1.2264x; 1.2264x over previous
//
#include <hip/hip_runtime.h>

typedef __bf16 bf16x8 __attribute__((ext_vector_type(8)));
typedef float f32x4 __attribute__((ext_vector_type(4)));
typedef unsigned short u16;
typedef u16 u16x8 __attribute__((ext_vector_type(8)));
typedef u16 u16x4 __attribute__((ext_vector_type(4)));

#define B_ 2
#define S_ 2048
#define D_ 4096
#define H_ 32
#define HD_ 128
#define SM_SCALE 0.08838834764831845f  // 1/sqrt(128)

__device__ __forceinline__ u16 f2bf(float f) {
  __bf16 h = (__bf16)f;
  return __builtin_bit_cast(unsigned short, h);
}
__device__ __forceinline__ float bf2f(u16 u) {
  return (float)__builtin_bit_cast(__bf16, u);
}

// async global->LDS, 16B per lane. LDS dest must be wave-uniform-base + lane*16.
#define GLD_TO_LDS16(gsrc, ldst)                                                     \
  __builtin_amdgcn_global_load_lds((__attribute__((address_space(1))) void*)(gsrc),  \
                                   (__attribute__((address_space(3))) void*)(ldst),  \
                                   16, 0, 0)

// ---------------- fp32 -> bf16 conversion ----------------
__global__ __launch_bounds__(256) void cvt_kernel(const float* __restrict__ src,
                                                  u16* __restrict__ dst, int n4) {
  int i = blockIdx.x * blockDim.x + threadIdx.x;
  int stride = gridDim.x * blockDim.x;
  for (; i < n4; i += stride) {
    float4 v = reinterpret_cast<const float4*>(src)[i];
    u16x4 o;
    o[0] = f2bf(v.x); o[1] = f2bf(v.y); o[2] = f2bf(v.z); o[3] = f2bf(v.w);
    reinterpret_cast<u16x4*>(dst)[i] = o;
  }
}

// ---------------- RoPE (in place on bf16 (B*S, D) tensor) ----------------
__global__ __launch_bounds__(256) void rope_kernel(u16* __restrict__ T,
                                                   const float* __restrict__ fc,
                                                   const float* __restrict__ fs) {
  const int n = B_ * S_ * D_ / 2;  // pairs
  int i = blockIdx.x * blockDim.x + threadIdx.x;
  int stride = gridDim.x * blockDim.x;
  unsigned int* Tp = reinterpret_cast<unsigned int*>(T);
  for (; i < n; i += stride) {
    int row = i >> 11;       // D/2 = 2048 pairs per row
    int pr = i & 2047;       // pair-in-row = h*64 + p
    int s = row & (S_ - 1);
    int p = pr & 63;
    float c = fc[(s << 6) + p];
    float sn = fs[(s << 6) + p];
    unsigned int u = Tp[i];  // pair offset in uints == i
    float xr = bf2f((u16)(u & 0xffff));
    float xi = bf2f((u16)(u >> 16));
    float orr = xr * c - xi * sn;
    float oii = xr * sn + xi * c;
    Tp[i] = (unsigned int)f2bf(orr) | ((unsigned int)f2bf(oii) << 16);
  }
}

// ---------------- GEMM: C[M,N] = A[M,K] * B[N,K]^T  (bf16 in, fp32 acc) ----------------
// 128x128 tile, BK=64, 4 waves (2x2), each wave 64x64 via 4x4 16x16x32 MFMA frags.
template <typename OutT>
__global__ __launch_bounds__(256) void gemm_bt_kernel(const u16* __restrict__ A,
                                                      const u16* __restrict__ Bw,
                                                      OutT* __restrict__ C,
                                                      int M, int N, int K) {
  __shared__ u16 As[128 * 64];
  __shared__ u16 Bs[128 * 64];
  const int tid = threadIdx.x;
  const int lane = tid & 63;
  const int w = tid >> 6;
  const int wr = w >> 1, wc = w & 1;
  const int nbx = N >> 7;
  const int nwg = (M >> 7) * nbx;
  int wg = blockIdx.x;
  if ((nwg & 7) == 0) wg = (wg & 7) * (nwg >> 3) + (wg >> 3);  // XCD swizzle (bijective)
  const int tr = wg / nbx, tc = wg % nbx;

  f32x4 acc[4][4] = {};

  const int ktn = K >> 6;
  for (int kt = 0; kt < ktn; ++kt) {
    const int k0 = kt << 6;
#pragma unroll
    for (int it = 0; it < 4; ++it) {
      int ff = it * 256 + tid;
      int row = ff >> 3, cc = ff & 7;
      int scc = cc ^ (row & 7);  // pre-swizzled source column-chunk
      GLD_TO_LDS16(A + (size_t)(tr * 128 + row) * K + k0 + scc * 8, &As[ff << 3]);
      GLD_TO_LDS16(Bw + (size_t)(tc * 128 + row) * K + k0 + scc * 8, &Bs[ff << 3]);
    }
    __syncthreads();
#pragma unroll
    for (int kk = 0; kk < 2; ++kk) {
      bf16x8 af[4], bfr[4];
#pragma unroll
      for (int m = 0; m < 4; ++m) {
        int row = wr * 64 + m * 16 + (lane & 15);
        int kc = kk * 4 + (lane >> 4);
        af[m] = *reinterpret_cast<const bf16x8*>(&As[(row << 6) + ((kc ^ (row & 7)) << 3)]);
      }
#pragma unroll
      for (int n = 0; n < 4; ++n) {
        int row = wc * 64 + n * 16 + (lane & 15);
        int kc = kk * 4 + (lane >> 4);
        bfr[n] = *reinterpret_cast<const bf16x8*>(&Bs[(row << 6) + ((kc ^ (row & 7)) << 3)]);
      }
#pragma unroll
      for (int m = 0; m < 4; ++m)
#pragma unroll
        for (int n = 0; n < 4; ++n)
          acc[m][n] = __builtin_amdgcn_mfma_f32_16x16x32_bf16(af[m], bfr[n], acc[m][n], 0, 0, 0);
    }
    __syncthreads();
  }
  const int r0 = tr * 128 + wr * 64;
  const int c0 = tc * 128 + wc * 64;
#pragma unroll
  for (int m = 0; m < 4; ++m)
#pragma unroll
    for (int n = 0; n < 4; ++n)
#pragma unroll
      for (int r = 0; r < 4; ++r) {
        int row = r0 + m * 16 + ((lane >> 4) << 2) + r;
        int col = c0 + n * 16 + (lane & 15);
        float v = acc[m][n][r];
        if constexpr (__is_same(OutT, float)) {
          C[(size_t)row * N + col] = v;
        } else {
          C[(size_t)row * N + col] = f2bf(v);
        }
      }
}

// ---------------- Flash attention (causal), bf16 QKV -> bf16 O ----------------
// v2: double-buffered K/V, ONE barrier per kv-tile, prefetch issued before compute,
// V reg->LDS writes after compute (issue-early/write-late), longest blocks first,
// setprio around MFMA clusters.
// grid: 1024 blocks = (16 q-tiles)*(64 bh); 4 waves, each owns 32 q-rows; KV tiles of 64.
__global__ __launch_bounds__(256) void attn_kernel(const u16* __restrict__ Q,
                                                   const u16* __restrict__ K,
                                                   const u16* __restrict__ V,
                                                   u16* __restrict__ O) {
  __shared__ u16 Ks[2][64 * 128];   // [kv][d], chunk-XOR swizzled
  __shared__ u16 Vt[2][128 * 64];   // [d][kv], chunk-XOR swizzled
  __shared__ u16 Ps[4][32 * 64];    // per-wave P (no cross-wave barrier needed)

  const int blk = blockIdx.x;
  const int qt = 15 - (blk >> 6);   // longest-running q-tiles launch first
  const int bh = blk & 63;
  const int b = bh >> 5, h = bh & 31;
  const int q0 = qt << 7;
  const int tid = threadIdx.x, lane = tid & 63, w = tid >> 6;
  const int wq0 = q0 + w * 32;

  // Q fragments straight from global (A-operand layout: row=lane&15, 8 contiguous k)
  bf16x8 qf[2][4];
#pragma unroll
  for (int m = 0; m < 2; ++m)
#pragma unroll
    for (int kk = 0; kk < 4; ++kk) {
      int row = wq0 + m * 16 + (lane & 15);
      int k = kk * 32 + ((lane >> 4) << 3);
      qf[m][kk] = *reinterpret_cast<const bf16x8*>(Q + (size_t)(b * S_ + row) * D_ + h * HD_ + k);
    }

  f32x4 oacc[2][8] = {};
  float mrun[2][4], lrun[2][4];
#pragma unroll
  for (int m = 0; m < 2; ++m)
#pragma unroll
    for (int r = 0; r < 4; ++r) { mrun[m][r] = -__builtin_inff(); lrun[m][r] = 0.f; }

  const int ntiles = 2 * qt + 2;  // covers kv <= q0+127
  u16x8 vreg[4];

  // ---- prologue: stage tile 0 into buffer 0 ----
  {
    const int kv0 = 0;
#pragma unroll
    for (int it = 0; it < 4; ++it) {
      int ff = it * 256 + tid;
      int row = ff >> 4, cc = ff & 15;
      int scc = cc ^ (row & 7);
      GLD_TO_LDS16(K + (size_t)(b * S_ + kv0 + row) * D_ + h * HD_ + scc * 8, &Ks[0][ff << 3]);
    }
#pragma unroll
    for (int it = 0; it < 4; ++it) {
      int ff = it * 256 + tid;
      int r = ff & 63, dc = ff >> 6;
      vreg[it] = *reinterpret_cast<const u16x8*>(V + (size_t)(b * S_ + kv0 + r) * D_ + h * HD_ + dc * 8);
    }
#pragma unroll
    for (int it = 0; it < 4; ++it) {
      int ff = it * 256 + tid;
      int r = ff & 63, dc = ff >> 6;
#pragma unroll
      for (int j = 0; j < 8; ++j) {
        int d = dc * 8 + j;
        Vt[0][(d << 6) + (((r >> 3) ^ (d & 7)) << 3) + (r & 7)] = vreg[it][j];
      }
    }
  }
  __syncthreads();

  for (int t = 0; t < ntiles; ++t) {
    const int cur = t & 1, nxt = cur ^ 1;
    const bool pre = (t + 1 < ntiles);
    // ---- issue prefetch for tile t+1 (no waits here) ----
    if (pre) {
      const int kv1 = (t + 1) << 6;
#pragma unroll
      for (int it = 0; it < 4; ++it) {
        int ff = it * 256 + tid;
        int row = ff >> 4, cc = ff & 15;
        int scc = cc ^ (row & 7);
        GLD_TO_LDS16(K + (size_t)(b * S_ + kv1 + row) * D_ + h * HD_ + scc * 8, &Ks[nxt][ff << 3]);
      }
#pragma unroll
      for (int it = 0; it < 4; ++it) {
        int ff = it * 256 + tid;
        int r = ff & 63, dc = ff >> 6;
        vreg[it] = *reinterpret_cast<const u16x8*>(V + (size_t)(b * S_ + kv1 + r) * D_ + h * HD_ + dc * 8);
      }
    }

    const int kv0 = t << 6;
    if (kv0 <= wq0 + 31) {  // wave-uniform causal skip
      // ---- S = Q K^T ----
      f32x4 s[2][4] = {};
      __builtin_amdgcn_s_setprio(1);
#pragma unroll
      for (int kk = 0; kk < 4; ++kk) {
        bf16x8 kf[4];
#pragma unroll
        for (int n = 0; n < 4; ++n) {
          int row = n * 16 + (lane & 15);
          int kc = kk * 4 + (lane >> 4);
          kf[n] = *reinterpret_cast<const bf16x8*>(&Ks[cur][(row << 7) + ((kc ^ (row & 7)) << 3)]);
        }
#pragma unroll
        for (int m = 0; m < 2; ++m)
#pragma unroll
          for (int n = 0; n < 4; ++n)
            s[m][n] = __builtin_amdgcn_mfma_f32_16x16x32_bf16(qf[m][kk], kf[n], s[m][n], 0, 0, 0);
      }
      __builtin_amdgcn_s_setprio(0);
      // causal mask on diagonal-crossing tiles
      if (kv0 + 63 > wq0) {
#pragma unroll
        for (int m = 0; m < 2; ++m)
#pragma unroll
          for (int n = 0; n < 4; ++n)
#pragma unroll
            for (int r = 0; r < 4; ++r) {
              int rowg = wq0 + m * 16 + ((lane >> 4) << 2) + r;
              int colg = kv0 + n * 16 + (lane & 15);
              if (colg > rowg) s[m][n][r] = -1e30f;
            }
      }
      // ---- online softmax ----
#pragma unroll
      for (int m = 0; m < 2; ++m) {
        float psc[4];
#pragma unroll
        for (int r = 0; r < 4; ++r) {
          float vmax = fmaxf(fmaxf(s[m][0][r], s[m][1][r]), fmaxf(s[m][2][r], s[m][3][r]));
          vmax = fmaxf(vmax, __shfl_xor(vmax, 1));
          vmax = fmaxf(vmax, __shfl_xor(vmax, 2));
          vmax = fmaxf(vmax, __shfl_xor(vmax, 4));
          vmax = fmaxf(vmax, __shfl_xor(vmax, 8));
          float mnew = fmaxf(mrun[m][r], vmax);
          float sc = __expf((mrun[m][r] - mnew) * SM_SCALE);
          mrun[m][r] = mnew;
          float psum = 0.f;
#pragma unroll
          for (int n = 0; n < 4; ++n) {
            float p = __expf((s[m][n][r] - mnew) * SM_SCALE);
            s[m][n][r] = p;
            psum += p;
          }
          psum += __shfl_xor(psum, 1);
          psum += __shfl_xor(psum, 2);
          psum += __shfl_xor(psum, 4);
          psum += __shfl_xor(psum, 8);
          lrun[m][r] = lrun[m][r] * sc + psum;
          psc[r] = sc;
        }
#pragma unroll
        for (int n = 0; n < 8; ++n)
#pragma unroll
          for (int r = 0; r < 4; ++r) oacc[m][n][r] *= psc[r];
      }
      // ---- P (bf16) -> per-wave LDS (C/D layout -> A layout through LDS) ----
      u16* P = Ps[w];
#pragma unroll
      for (int m = 0; m < 2; ++m)
#pragma unroll
        for (int n = 0; n < 4; ++n)
#pragma unroll
          for (int r = 0; r < 4; ++r) {
            int prow = m * 16 + ((lane >> 4) << 2) + r;
            int pcol = n * 16 + (lane & 15);
            P[(prow << 6) + (((pcol >> 3) ^ (prow & 7)) << 3) + (pcol & 7)] = f2bf(s[m][n][r]);
          }
      // ---- O += P V ----
      __builtin_amdgcn_s_setprio(1);
#pragma unroll
      for (int kk2 = 0; kk2 < 2; ++kk2) {
        bf16x8 pa[2];
#pragma unroll
        for (int m = 0; m < 2; ++m) {
          int prow = m * 16 + (lane & 15);
          int kc = kk2 * 4 + (lane >> 4);
          pa[m] = *reinterpret_cast<const bf16x8*>(&P[(prow << 6) + ((kc ^ (prow & 7)) << 3)]);
        }
#pragma unroll
        for (int n = 0; n < 8; ++n) {
          int vrow = n * 16 + (lane & 15);
          int kc = kk2 * 4 + (lane >> 4);
          bf16x8 vf = *reinterpret_cast<const bf16x8*>(&Vt[cur][(vrow << 6) + ((kc ^ (vrow & 7)) << 3)]);
#pragma unroll
          for (int m = 0; m < 2; ++m)
            oacc[m][n] = __builtin_amdgcn_mfma_f32_16x16x32_bf16(pa[m], vf, oacc[m][n], 0, 0, 0);
        }
      }
      __builtin_amdgcn_s_setprio(0);
    }

    // ---- late V write for tile t+1 (waits vmcnt for vreg only here) ----
    if (pre) {
#pragma unroll
      for (int it = 0; it < 4; ++it) {
        int ff = it * 256 + tid;
        int r = ff & 63, dc = ff >> 6;
#pragma unroll
        for (int j = 0; j < 8; ++j) {
          int d = dc * 8 + j;
          Vt[nxt][(d << 6) + (((r >> 3) ^ (d & 7)) << 3) + (r & 7)] = vreg[it][j];
        }
      }
    }
    __syncthreads();  // single barrier per tile
  }

  // epilogue: O / l -> bf16
#pragma unroll
  for (int m = 0; m < 2; ++m)
#pragma unroll
    for (int n = 0; n < 8; ++n)
#pragma unroll
      for (int r = 0; r < 4; ++r) {
        int rowg = wq0 + m * 16 + ((lane >> 4) << 2) + r;
        int colg = n * 16 + (lane & 15);
        float v = oacc[m][n][r] / lrun[m][r];
        O[(size_t)(b * S_ + rowg) * D_ + h * HD_ + colg] = f2bf(v);
      }
}

// ---------------- launcher ----------------
extern "C" void kernel_launch(void* const* d_in, const int* in_sizes, int n_in,
                              void* d_out, int out_size, void* d_ws, size_t ws_size,
                              hipStream_t stream) {
  const float* x = (const float*)d_in[0];
  const float* wq = (const float*)d_in[1];
  const float* wk = (const float*)d_in[2];
  const float* wv = (const float*)d_in[3];
  const float* wo = (const float*)d_in[4];
  const float* fc = (const float*)d_in[5];
  const float* fs = (const float*)d_in[6];
  float* out = (float*)d_out;

  const size_t SLOT = (size_t)B_ * S_ * D_;  // 16,777,216 elements
  u16* ws = (u16*)d_ws;
  u16* wqb = ws + 0 * SLOT;
  u16* wkb = ws + 1 * SLOT;
  u16* wvb = ws + 2 * SLOT;
  u16* wob = ws + 3 * SLOT;
  u16* xb  = ws + 4 * SLOT;  // reused as attention output O after QKV GEMMs
  u16* Qb  = ws + 5 * SLOT;
  u16* Kb  = ws + 6 * SLOT;
  u16* Vb  = ws + 7 * SLOT;
  u16* Ob  = xb;

  const int n4 = (int)(SLOT / 4);
  cvt_kernel<<<2048, 256, 0, stream>>>(x, xb, n4);
  cvt_kernel<<<2048, 256, 0, stream>>>(wq, wqb, n4);
  cvt_kernel<<<2048, 256, 0, stream>>>(wk, wkb, n4);
  cvt_kernel<<<2048, 256, 0, stream>>>(wv, wvb, n4);
  cvt_kernel<<<2048, 256, 0, stream>>>(wo, wob, n4);

  gemm_bt_kernel<u16><<<1024, 256, 0, stream>>>(xb, wqb, Qb, B_ * S_, D_, D_);
  gemm_bt_kernel<u16><<<1024, 256, 0, stream>>>(xb, wkb, Kb, B_ * S_, D_, D_);
  gemm_bt_kernel<u16><<<1024, 256, 0, stream>>>(xb, wvb, Vb, B_ * S_, D_, D_);

  rope_kernel<<<2048, 256, 0, stream>>>(Qb, fc, fs);
  rope_kernel<<<2048, 256, 0, stream>>>(Kb, fc, fs);

  attn_kernel<<<1024, 256, 0, stream>>>(Qb, Kb, Vb, Ob);

  gemm_bt_kernel<float><<<1024, 256, 0, stream>>>(Ob, wob, out, B_ * S_, D_, D_);
}

// Round 3
// 1153.794 us; speedup vs baseline: 1.2280x; 1.0013x over previous
//
#include <hip/hip_runtime.h>

typedef __bf16 bf16x8 __attribute__((ext_vector_type(8)));
typedef float f32x4 __attribute__((ext_vector_type(4)));
typedef unsigned short u16;
typedef u16 u16x8 __attribute__((ext_vector_type(8)));
typedef u16 u16x4 __attribute__((ext_vector_type(4)));

#define B_ 2
#define S_ 2048
#define D_ 4096
#define H_ 32
#define HD_ 128
#define SM_SCALE 0.08838834764831845f  // 1/sqrt(128)

__device__ __forceinline__ u16 f2bf(float f) {
  __bf16 h = (__bf16)f;
  return __builtin_bit_cast(unsigned short, h);
}
__device__ __forceinline__ float bf2f(u16 u) {
  return (float)__builtin_bit_cast(__bf16, u);
}

// async global->LDS, 16B per lane. LDS dest must be wave-uniform base + lane*16.
#define GLD_TO_LDS16(gsrc, ldst)                                                     \
  __builtin_amdgcn_global_load_lds((__attribute__((address_space(1))) void*)(gsrc),  \
                                   (__attribute__((address_space(3))) void*)(ldst),  \
                                   16, 0, 0)

// ---------------- fp32 -> bf16 conversion ----------------
__global__ __launch_bounds__(256) void cvt_kernel(const float* __restrict__ src,
                                                  u16* __restrict__ dst, int n4) {
  int i = blockIdx.x * blockDim.x + threadIdx.x;
  int stride = gridDim.x * blockDim.x;
  for (; i < n4; i += stride) {
    float4 v = reinterpret_cast<const float4*>(src)[i];
    u16x4 o;
    o[0] = f2bf(v.x); o[1] = f2bf(v.y); o[2] = f2bf(v.z); o[3] = f2bf(v.w);
    reinterpret_cast<u16x4*>(dst)[i] = o;
  }
}

// ---------------- RoPE (in place on bf16 (B*S, D) tensor) ----------------
__global__ __launch_bounds__(256) void rope_kernel(u16* __restrict__ T,
                                                   const float* __restrict__ fc,
                                                   const float* __restrict__ fs) {
  const int n = B_ * S_ * D_ / 2;  // pairs
  int i = blockIdx.x * blockDim.x + threadIdx.x;
  int stride = gridDim.x * blockDim.x;
  unsigned int* Tp = reinterpret_cast<unsigned int*>(T);
  for (; i < n; i += stride) {
    int row = i >> 11;       // D/2 = 2048 pairs per row
    int pr = i & 2047;       // pair-in-row = h*64 + p
    int s = row & (S_ - 1);
    int p = pr & 63;
    float c = fc[(s << 6) + p];
    float sn = fs[(s << 6) + p];
    unsigned int u = Tp[i];  // pair offset in uints == i
    float xr = bf2f((u16)(u & 0xffff));
    float xi = bf2f((u16)(u >> 16));
    float orr = xr * c - xi * sn;
    float oii = xr * sn + xi * c;
    Tp[i] = (unsigned int)f2bf(orr) | ((unsigned int)f2bf(oii) << 16);
  }
}

// ---------------- GEMM v3: C[M,N] = A[M,K] * B[N,K]^T, 256^2 tile, deep pipeline ------
// 512 threads = 8 waves (2M x 4N), per-wave output 128x64 (8x4 frags of 16x16).
// BK=32 (== MFMA K), quad-buffered LDS (4 x (A 16KB + B 16KB) = 128 KB), staged 3
// K-tiles ahead. Counted per-wave vmcnt(8) + raw s_barrier per K-tile (never drains
// to 0 in the main loop); one inner phase barrier; setprio around MFMA clusters.
// LDS chunk-XOR swizzle c ^= (row ^ row>>2)&3 (2-way conflicts max, free per m136),
// inverse-applied at the global source (both-sides-or-neither).
template <typename OutT>
__global__ __launch_bounds__(512, 2) void gemm256_kernel(const u16* __restrict__ A,
                                                         const u16* __restrict__ Bw,
                                                         OutT* __restrict__ C,
                                                         int M, int N, int K) {
  __shared__ u16 As[4][8192];  // [buf][row*32 + chunk*8], 256 rows x 32 cols bf16
  __shared__ u16 Bs[4][8192];
  const int tid = threadIdx.x;
  const int lane = tid & 63;
  const int w = tid >> 6;   // 0..7
  const int wr = w >> 2;    // 0..1  (M half)
  const int wn = w & 3;     // 0..3  (N quarter)
  const int nbx = N >> 8;
  const int nwg = (M >> 8) * nbx;
  int wg = blockIdx.x;
  if ((nwg & 7) == 0) wg = (wg & 7) * (nwg >> 3) + (wg >> 3);  // XCD swizzle (bijective)
  const int tr = wg / nbx, tc = wg % nbx;

  const size_t arow0 = (size_t)tr * 256;
  const size_t brow0 = (size_t)tc * 256;
  const int KT = K >> 5;

  // stage K-tile ti into buffer bi: 4 global_load_lds per thread (A x2, B x2)
  auto stage = [&](int ti, int bi) {
    const int k0 = ti << 5;
#pragma unroll
    for (int i = 0; i < 2; ++i) {
      int q = ((i << 3) + w) * 64 + lane;  // LDS chunk index 0..1023
      int row = q >> 2;
      int c = (q & 3) ^ ((row ^ (row >> 2)) & 3);  // inverse swizzle at source
      GLD_TO_LDS16(A + (arow0 + row) * K + k0 + c * 8, &As[bi][q << 3]);
    }
#pragma unroll
    for (int i = 0; i < 2; ++i) {
      int q = ((i << 3) + w) * 64 + lane;
      int row = q >> 2;
      int c = (q & 3) ^ ((row ^ (row >> 2)) & 3);
      GLD_TO_LDS16(Bw + (brow0 + row) * K + k0 + c * 8, &Bs[bi][q << 3]);
    }
  };

  f32x4 acc[8][4] = {};

  stage(0, 0);
  if (KT > 1) stage(1, 1);
  if (KT > 2) stage(2, 2);

  for (int t = 0; t < KT; ++t) {
    const int cur = t & 3;
    const int rem = KT - 1 - t;
    // wait for THIS wave's tile-t loads; keep younger tiles' loads in flight
    if (rem >= 2)      asm volatile("s_waitcnt vmcnt(8)" ::: "memory");
    else if (rem == 1) asm volatile("s_waitcnt vmcnt(4)" ::: "memory");
    else               asm volatile("s_waitcnt vmcnt(0)" ::: "memory");
    asm volatile("s_barrier" ::: "memory");  // all waves' shares of tile t in LDS

    if (t + 3 < KT) stage(t + 3, (t + 3) & 3);  // issue-early prefetch

    // B fragments (held across both phases)
    bf16x8 bfr[4];
#pragma unroll
    for (int n = 0; n < 4; ++n) {
      int row = wn * 64 + n * 16 + (lane & 15);
      int c = (lane >> 4) ^ ((row ^ (row >> 2)) & 3);
      bfr[n] = *reinterpret_cast<const bf16x8*>(&Bs[cur][(row << 5) + (c << 3)]);
    }
#pragma unroll
    for (int ph = 0; ph < 2; ++ph) {
      bf16x8 af[4];
#pragma unroll
      for (int m = 0; m < 4; ++m) {
        int row = wr * 128 + (ph * 4 + m) * 16 + (lane & 15);
        int c = (lane >> 4) ^ ((row ^ (row >> 2)) & 3);
        af[m] = *reinterpret_cast<const bf16x8*>(&As[cur][(row << 5) + (c << 3)]);
      }
      __builtin_amdgcn_s_setprio(1);
#pragma unroll
      for (int m = 0; m < 4; ++m)
#pragma unroll
        for (int n = 0; n < 4; ++n)
          acc[ph * 4 + m][n] =
              __builtin_amdgcn_mfma_f32_16x16x32_bf16(af[m], bfr[n], acc[ph * 4 + m][n], 0, 0, 0);
      __builtin_amdgcn_s_setprio(0);
      if (ph == 0) __builtin_amdgcn_s_barrier();  // phase split (wave role diversity)
    }
  }

  const size_t r0 = arow0 + wr * 128;
  const size_t c0 = (size_t)tc * 256 + wn * 64;
#pragma unroll
  for (int m = 0; m < 8; ++m)
#pragma unroll
    for (int n = 0; n < 4; ++n)
#pragma unroll
      for (int r = 0; r < 4; ++r) {
        size_t row = r0 + m * 16 + ((lane >> 4) << 2) + r;
        size_t col = c0 + n * 16 + (lane & 15);
        float v = acc[m][n][r];
        if constexpr (__is_same(OutT, float)) {
          C[row * N + col] = v;
        } else {
          C[row * N + col] = f2bf(v);
        }
      }
}

// ---------------- Flash attention (causal), bf16 QKV -> bf16 O ----------------
// v2: double-buffered K/V, ONE barrier per kv-tile, prefetch issued before compute,
// V reg->LDS writes after compute (issue-early/write-late), longest blocks first,
// setprio around MFMA clusters.
__global__ __launch_bounds__(256) void attn_kernel(const u16* __restrict__ Q,
                                                   const u16* __restrict__ K,
                                                   const u16* __restrict__ V,
                                                   u16* __restrict__ O) {
  __shared__ u16 Ks[2][64 * 128];   // [kv][d], chunk-XOR swizzled
  __shared__ u16 Vt[2][128 * 64];   // [d][kv], chunk-XOR swizzled
  __shared__ u16 Ps[4][32 * 64];    // per-wave P

  const int blk = blockIdx.x;
  const int qt = 15 - (blk >> 6);   // longest-running q-tiles launch first
  const int bh = blk & 63;
  const int b = bh >> 5, h = bh & 31;
  const int q0 = qt << 7;
  const int tid = threadIdx.x, lane = tid & 63, w = tid >> 6;
  const int wq0 = q0 + w * 32;

  bf16x8 qf[2][4];
#pragma unroll
  for (int m = 0; m < 2; ++m)
#pragma unroll
    for (int kk = 0; kk < 4; ++kk) {
      int row = wq0 + m * 16 + (lane & 15);
      int k = kk * 32 + ((lane >> 4) << 3);
      qf[m][kk] = *reinterpret_cast<const bf16x8*>(Q + (size_t)(b * S_ + row) * D_ + h * HD_ + k);
    }

  f32x4 oacc[2][8] = {};
  float mrun[2][4], lrun[2][4];
#pragma unroll
  for (int m = 0; m < 2; ++m)
#pragma unroll
    for (int r = 0; r < 4; ++r) { mrun[m][r] = -__builtin_inff(); lrun[m][r] = 0.f; }

  const int ntiles = 2 * qt + 2;
  u16x8 vreg[4];

  {
    const int kv0 = 0;
#pragma unroll
    for (int it = 0; it < 4; ++it) {
      int ff = it * 256 + tid;
      int row = ff >> 4, cc = ff & 15;
      int scc = cc ^ (row & 7);
      GLD_TO_LDS16(K + (size_t)(b * S_ + kv0 + row) * D_ + h * HD_ + scc * 8, &Ks[0][ff << 3]);
    }
#pragma unroll
    for (int it = 0; it < 4; ++it) {
      int ff = it * 256 + tid;
      int r = ff & 63, dc = ff >> 6;
      vreg[it] = *reinterpret_cast<const u16x8*>(V + (size_t)(b * S_ + kv0 + r) * D_ + h * HD_ + dc * 8);
    }
#pragma unroll
    for (int it = 0; it < 4; ++it) {
      int ff = it * 256 + tid;
      int r = ff & 63, dc = ff >> 6;
#pragma unroll
      for (int j = 0; j < 8; ++j) {
        int d = dc * 8 + j;
        Vt[0][(d << 6) + (((r >> 3) ^ (d & 7)) << 3) + (r & 7)] = vreg[it][j];
      }
    }
  }
  __syncthreads();

  for (int t = 0; t < ntiles; ++t) {
    const int cur = t & 1, nxt = cur ^ 1;
    const bool pre = (t + 1 < ntiles);
    if (pre) {
      const int kv1 = (t + 1) << 6;
#pragma unroll
      for (int it = 0; it < 4; ++it) {
        int ff = it * 256 + tid;
        int row = ff >> 4, cc = ff & 15;
        int scc = cc ^ (row & 7);
        GLD_TO_LDS16(K + (size_t)(b * S_ + kv1 + row) * D_ + h * HD_ + scc * 8, &Ks[nxt][ff << 3]);
      }
#pragma unroll
      for (int it = 0; it < 4; ++it) {
        int ff = it * 256 + tid;
        int r = ff & 63, dc = ff >> 6;
        vreg[it] = *reinterpret_cast<const u16x8*>(V + (size_t)(b * S_ + kv1 + r) * D_ + h * HD_ + dc * 8);
      }
    }

    const int kv0 = t << 6;
    if (kv0 <= wq0 + 31) {
      f32x4 s[2][4] = {};
      __builtin_amdgcn_s_setprio(1);
#pragma unroll
      for (int kk = 0; kk < 4; ++kk) {
        bf16x8 kf[4];
#pragma unroll
        for (int n = 0; n < 4; ++n) {
          int row = n * 16 + (lane & 15);
          int kc = kk * 4 + (lane >> 4);
          kf[n] = *reinterpret_cast<const bf16x8*>(&Ks[cur][(row << 7) + ((kc ^ (row & 7)) << 3)]);
        }
#pragma unroll
        for (int m = 0; m < 2; ++m)
#pragma unroll
          for (int n = 0; n < 4; ++n)
            s[m][n] = __builtin_amdgcn_mfma_f32_16x16x32_bf16(qf[m][kk], kf[n], s[m][n], 0, 0, 0);
      }
      __builtin_amdgcn_s_setprio(0);
      if (kv0 + 63 > wq0) {
#pragma unroll
        for (int m = 0; m < 2; ++m)
#pragma unroll
          for (int n = 0; n < 4; ++n)
#pragma unroll
            for (int r = 0; r < 4; ++r) {
              int rowg = wq0 + m * 16 + ((lane >> 4) << 2) + r;
              int colg = kv0 + n * 16 + (lane & 15);
              if (colg > rowg) s[m][n][r] = -1e30f;
            }
      }
#pragma unroll
      for (int m = 0; m < 2; ++m) {
        float psc[4];
#pragma unroll
        for (int r = 0; r < 4; ++r) {
          float vmax = fmaxf(fmaxf(s[m][0][r], s[m][1][r]), fmaxf(s[m][2][r], s[m][3][r]));
          vmax = fmaxf(vmax, __shfl_xor(vmax, 1));
          vmax = fmaxf(vmax, __shfl_xor(vmax, 2));
          vmax = fmaxf(vmax, __shfl_xor(vmax, 4));
          vmax = fmaxf(vmax, __shfl_xor(vmax, 8));
          float mnew = fmaxf(mrun[m][r], vmax);
          float sc = __expf((mrun[m][r] - mnew) * SM_SCALE);
          mrun[m][r] = mnew;
          float psum = 0.f;
#pragma unroll
          for (int n = 0; n < 4; ++n) {
            float p = __expf((s[m][n][r] - mnew) * SM_SCALE);
            s[m][n][r] = p;
            psum += p;
          }
          psum += __shfl_xor(psum, 1);
          psum += __shfl_xor(psum, 2);
          psum += __shfl_xor(psum, 4);
          psum += __shfl_xor(psum, 8);
          lrun[m][r] = lrun[m][r] * sc + psum;
          psc[r] = sc;
        }
#pragma unroll
        for (int n = 0; n < 8; ++n)
#pragma unroll
          for (int r = 0; r < 4; ++r) oacc[m][n][r] *= psc[r];
      }
      u16* P = Ps[w];
#pragma unroll
      for (int m = 0; m < 2; ++m)
#pragma unroll
        for (int n = 0; n < 4; ++n)
#pragma unroll
          for (int r = 0; r < 4; ++r) {
            int prow = m * 16 + ((lane >> 4) << 2) + r;
            int pcol = n * 16 + (lane & 15);
            P[(prow << 6) + (((pcol >> 3) ^ (prow & 7)) << 3) + (pcol & 7)] = f2bf(s[m][n][r]);
          }
      __builtin_amdgcn_s_setprio(1);
#pragma unroll
      for (int kk2 = 0; kk2 < 2; ++kk2) {
        bf16x8 pa[2];
#pragma unroll
        for (int m = 0; m < 2; ++m) {
          int prow = m * 16 + (lane & 15);
          int kc = kk2 * 4 + (lane >> 4);
          pa[m] = *reinterpret_cast<const bf16x8*>(&P[(prow << 6) + ((kc ^ (prow & 7)) << 3)]);
        }
#pragma unroll
        for (int n = 0; n < 8; ++n) {
          int vrow = n * 16 + (lane & 15);
          int kc = kk2 * 4 + (lane >> 4);
          bf16x8 vf = *reinterpret_cast<const bf16x8*>(&Vt[cur][(vrow << 6) + ((kc ^ (vrow & 7)) << 3)]);
#pragma unroll
          for (int m = 0; m < 2; ++m)
            oacc[m][n] = __builtin_amdgcn_mfma_f32_16x16x32_bf16(pa[m], vf, oacc[m][n], 0, 0, 0);
        }
      }
      __builtin_amdgcn_s_setprio(0);
    }

    if (pre) {
#pragma unroll
      for (int it = 0; it < 4; ++it) {
        int ff = it * 256 + tid;
        int r = ff & 63, dc = ff >> 6;
#pragma unroll
        for (int j = 0; j < 8; ++j) {
          int d = dc * 8 + j;
          Vt[nxt][(d << 6) + (((r >> 3) ^ (d & 7)) << 3) + (r & 7)] = vreg[it][j];
        }
      }
    }
    __syncthreads();
  }

#pragma unroll
  for (int m = 0; m < 2; ++m)
#pragma unroll
    for (int n = 0; n < 8; ++n)
#pragma unroll
      for (int r = 0; r < 4; ++r) {
        int rowg = wq0 + m * 16 + ((lane >> 4) << 2) + r;
        int colg = n * 16 + (lane & 15);
        float v = oacc[m][n][r] / lrun[m][r];
        O[(size_t)(b * S_ + rowg) * D_ + h * HD_ + colg] = f2bf(v);
      }
}

// ---------------- launcher ----------------
extern "C" void kernel_launch(void* const* d_in, const int* in_sizes, int n_in,
                              void* d_out, int out_size, void* d_ws, size_t ws_size,
                              hipStream_t stream) {
  const float* x = (const float*)d_in[0];
  const float* wq = (const float*)d_in[1];
  const float* wk = (const float*)d_in[2];
  const float* wv = (const float*)d_in[3];
  const float* wo = (const float*)d_in[4];
  const float* fc = (const float*)d_in[5];
  const float* fs = (const float*)d_in[6];
  float* out = (float*)d_out;

  const size_t SLOT = (size_t)B_ * S_ * D_;  // 16,777,216 elements
  u16* ws = (u16*)d_ws;
  u16* wqb = ws + 0 * SLOT;
  u16* wkb = ws + 1 * SLOT;
  u16* wvb = ws + 2 * SLOT;
  u16* wob = ws + 3 * SLOT;
  u16* xb  = ws + 4 * SLOT;  // reused as attention output O after QKV GEMMs
  u16* Qb  = ws + 5 * SLOT;
  u16* Kb  = ws + 6 * SLOT;
  u16* Vb  = ws + 7 * SLOT;
  u16* Ob  = xb;

  const int n4 = (int)(SLOT / 4);
  cvt_kernel<<<2048, 256, 0, stream>>>(x, xb, n4);
  cvt_kernel<<<2048, 256, 0, stream>>>(wq, wqb, n4);
  cvt_kernel<<<2048, 256, 0, stream>>>(wk, wkb, n4);
  cvt_kernel<<<2048, 256, 0, stream>>>(wv, wvb, n4);
  cvt_kernel<<<2048, 256, 0, stream>>>(wo, wob, n4);

  gemm256_kernel<u16><<<256, 512, 0, stream>>>(xb, wqb, Qb, B_ * S_, D_, D_);
  gemm256_kernel<u16><<<256, 512, 0, stream>>>(xb, wkb, Kb, B_ * S_, D_, D_);
  gemm256_kernel<u16><<<256, 512, 0, stream>>>(xb, wvb, Vb, B_ * S_, D_, D_);

  rope_kernel<<<2048, 256, 0, stream>>>(Qb, fc, fs);
  rope_kernel<<<2048, 256, 0, stream>>>(Kb, fc, fs);

  attn_kernel<<<1024, 256, 0, stream>>>(Qb, Kb, Vb, Ob);

  gemm256_kernel<float><<<256, 512, 0, stream>>>(Ob, wob, out, B_ * S_, D_, D_);
}

// Round 5
// 1015.518 us; speedup vs baseline: 1.3952x; 1.1362x over previous
//
#include <hip/hip_runtime.h>

typedef __bf16 bf16x8 __attribute__((ext_vector_type(8)));
typedef float f32x4 __attribute__((ext_vector_type(4)));
typedef unsigned short u16;
typedef u16 u16x8 __attribute__((ext_vector_type(8)));
typedef u16 u16x4 __attribute__((ext_vector_type(4)));

#define B_ 2
#define S_ 2048
#define D_ 4096
#define H_ 32
#define HD_ 128
#define SM_SCALE 0.08838834764831845f  // 1/sqrt(128)

__device__ __forceinline__ u16 f2bf(float f) {
  __bf16 h = (__bf16)f;
  return __builtin_bit_cast(unsigned short, h);
}
__device__ __forceinline__ float bf2f(u16 u) {
  return (float)__builtin_bit_cast(__bf16, u);
}

// async global->LDS, 16B per lane. LDS dest must be wave-uniform base + lane*16.
#define GLD_TO_LDS16(gsrc, ldst)                                                     \
  __builtin_amdgcn_global_load_lds((__attribute__((address_space(1))) void*)(gsrc),  \
                                   (__attribute__((address_space(3))) void*)(ldst),  \
                                   16, 0, 0)

// ---------------- fp32 -> bf16 conversion ----------------
__global__ __launch_bounds__(256) void cvt_kernel(const float* __restrict__ src,
                                                  u16* __restrict__ dst, int n4) {
  int i = blockIdx.x * blockDim.x + threadIdx.x;
  int stride = gridDim.x * blockDim.x;
  for (; i < n4; i += stride) {
    float4 v = reinterpret_cast<const float4*>(src)[i];
    u16x4 o;
    o[0] = f2bf(v.x); o[1] = f2bf(v.y); o[2] = f2bf(v.z); o[3] = f2bf(v.w);
    reinterpret_cast<u16x4*>(dst)[i] = o;
  }
}

// ---------------- RoPE (in place on bf16 (B*S, D) tensor) ----------------
__global__ __launch_bounds__(256) void rope_kernel(u16* __restrict__ T,
                                                   const float* __restrict__ fc,
                                                   const float* __restrict__ fs) {
  const int n = B_ * S_ * D_ / 2;  // pairs
  int i = blockIdx.x * blockDim.x + threadIdx.x;
  int stride = gridDim.x * blockDim.x;
  unsigned int* Tp = reinterpret_cast<unsigned int*>(T);
  for (; i < n; i += stride) {
    int row = i >> 11;       // D/2 = 2048 pairs per row
    int pr = i & 2047;       // pair-in-row = h*64 + p
    int s = row & (S_ - 1);
    int p = pr & 63;
    float c = fc[(s << 6) + p];
    float sn = fs[(s << 6) + p];
    unsigned int u = Tp[i];  // pair offset in uints == i
    float xr = bf2f((u16)(u & 0xffff));
    float xi = bf2f((u16)(u >> 16));
    float orr = xr * c - xi * sn;
    float oii = xr * sn + xi * c;
    Tp[i] = (unsigned int)f2bf(orr) | ((unsigned int)f2bf(oii) << 16);
  }
}

// ---------------- GEMM v4: m201-style 256^2 8-phase schedule ----------------
// C[M,N] = A[M,K] * B[N,K]^T, bf16 in, fp32 acc. 512 threads = 8 waves (2Mx4N).
// BK=64, LDS = 2 dbuf x 2 half x [128 rows][64 cols] x {A,B} = 128 KB.
// Per-wave output 128x64 SPLIT across halves: rows mq*128+wr*64+m*16, cols
// nq*128+wn*32+n*16. Phase (mq,nq) reads exactly A-half mq + B-half nq, so
// regions free early and the half-tile stagger is race-free:
//   group k phases: p1(0,0)+stageA(k+1,h1) p2(0,1)+stageB(k+1,h1)
//                   p3(1,0)+stageA(k+2,h0) p4(1,1)+stageB(k+2,h0)+vmcnt(4)
// vmcnt(4) at p4 (oldest-4 rule) => tile k+1 fully in LDS before group k+1,
// while tile k+2's first 2 half-tiles stay in flight. Never drains in main loop.
// Swizzle: chunk c8 ^= (row&7), applied at gl_lds SOURCE and ds_read (rule 21).

__device__ __forceinline__ void ds_afrags(const u16* half_base, int wr, int lane,
                                          bf16x8 af[2][4]) {
#pragma unroll
  for (int ks = 0; ks < 2; ++ks)
#pragma unroll
    for (int m = 0; m < 4; ++m) {
      int rr = wr * 64 + m * 16 + (lane & 15);
      int c8 = (ks * 4 + (lane >> 4)) ^ (rr & 7);
      af[ks][m] = *reinterpret_cast<const bf16x8*>(half_base + rr * 64 + c8 * 8);
    }
}
__device__ __forceinline__ void ds_bfrags(const u16* half_base, int wn, int lane,
                                          bf16x8 bfr[2][2]) {
#pragma unroll
  for (int ks = 0; ks < 2; ++ks)
#pragma unroll
    for (int n = 0; n < 2; ++n) {
      int rr = wn * 32 + n * 16 + (lane & 15);
      int c8 = (ks * 4 + (lane >> 4)) ^ (rr & 7);
      bfr[ks][n] = *reinterpret_cast<const bf16x8*>(half_base + rr * 64 + c8 * 8);
    }
}

#define MFMA_QUAD(MQ, NQ)                                                        \
  do {                                                                           \
    __builtin_amdgcn_s_setprio(1);                                               \
    _Pragma("unroll") for (int ks = 0; ks < 2; ++ks)                             \
      _Pragma("unroll") for (int m = 0; m < 4; ++m)                              \
        _Pragma("unroll") for (int n = 0; n < 2; ++n)                            \
          acc[(MQ) * 4 + m][(NQ) * 2 + n] =                                      \
              __builtin_amdgcn_mfma_f32_16x16x32_bf16(                           \
                  af[ks][m], bfr[ks][n], acc[(MQ) * 4 + m][(NQ) * 2 + n], 0, 0, 0); \
    __builtin_amdgcn_s_setprio(0);                                               \
  } while (0)

#define PRE_MFMA_SYNC()                                   \
  do {                                                    \
    __builtin_amdgcn_s_barrier();                         \
    asm volatile("s_waitcnt lgkmcnt(0)" ::: "memory");    \
    __builtin_amdgcn_sched_barrier(0);                    \
  } while (0)

#define POST_MFMA_SYNC()                                  \
  do {                                                    \
    __builtin_amdgcn_s_barrier();                         \
    __builtin_amdgcn_sched_barrier(0);                    \
  } while (0)

template <typename OutT>
__global__ __launch_bounds__(512, 2) void gemm256_kernel(const u16* __restrict__ A,
                                                         const u16* __restrict__ Bw,
                                                         OutT* __restrict__ C,
                                                         int M, int N, int K) {
  __shared__ u16 As[2][2][8192];  // [dbuf][half][r*64 + c]
  __shared__ u16 Bs[2][2][8192];
  const int tid = threadIdx.x;
  const int lane = tid & 63;
  const int w = tid >> 6;   // 0..7
  const int wr = w >> 2;    // 0..1
  const int wn = w & 3;     // 0..3
  const int nbx = N >> 8;
  const int nwg = (M >> 8) * nbx;
  int wg = blockIdx.x;
  if ((nwg & 7) == 0) wg = (wg & 7) * (nwg >> 3) + (wg >> 3);  // XCD swizzle
  const int tr = wg / nbx, tc = wg % nbx;

  const size_t arow0 = (size_t)tr * 256;
  const size_t brow0 = (size_t)tc * 256;
  const int KT = K >> 6;

  // stage one half-tile (128 rows x 64 cols) = 2 gl_lds/thread, linear LDS dest,
  // inverse-swizzled global source.
  auto stageA = [&](int t, int half) {
    if (t >= KT) return;
    const int k0 = t << 6;
    u16* base = &As[t & 1][half][0];
#pragma unroll
    for (int i = 0; i < 2; ++i) {
      int q = i * 512 + tid;
      int r = q >> 3;
      int c8 = (q & 7) ^ (r & 7);
      GLD_TO_LDS16(A + (arow0 + half * 128 + r) * K + k0 + c8 * 8, base + q * 8);
    }
  };
  auto stageB = [&](int t, int half) {
    if (t >= KT) return;
    const int k0 = t << 6;
    u16* base = &Bs[t & 1][half][0];
#pragma unroll
    for (int i = 0; i < 2; ++i) {
      int q = i * 512 + tid;
      int r = q >> 3;
      int c8 = (q & 7) ^ (r & 7);
      GLD_TO_LDS16(Bw + (brow0 + half * 128 + r) * K + k0 + c8 * 8, base + q * 8);
    }
  };

  f32x4 acc[8][4] = {};

  // ---- prologue: tile0 (4 half-tiles) + tile1's A-h0, B-h0 ----
  stageA(0, 0); stageB(0, 0); stageA(0, 1); stageB(0, 1);
  stageA(1, 0); stageB(1, 0);
  asm volatile("s_waitcnt vmcnt(4)" ::: "memory");  // tile0 landed; tile1 h0s in flight
  __builtin_amdgcn_s_barrier();
  __builtin_amdgcn_sched_barrier(0);

  for (int k = 0; k < KT; ++k) {
    const int buf = k & 1;
    bf16x8 af[2][4], bfr[2][2];

    // ---- phase 1: (mq0, nq0) ----
    ds_afrags(&As[buf][0][0], wr, lane, af);
    ds_bfrags(&Bs[buf][0][0], wn, lane, bfr);
    stageA(k + 1, 1);
    PRE_MFMA_SYNC();
    MFMA_QUAD(0, 0);
    POST_MFMA_SYNC();

    // ---- phase 2: (mq0, nq1) — af reused ----
    ds_bfrags(&Bs[buf][1][0], wn, lane, bfr);
    stageB(k + 1, 1);
    PRE_MFMA_SYNC();
    MFMA_QUAD(0, 1);
    POST_MFMA_SYNC();

    // ---- phase 3: (mq1, nq0) ----
    ds_afrags(&As[buf][1][0], wr, lane, af);
    ds_bfrags(&Bs[buf][0][0], wn, lane, bfr);
    stageA(k + 2, 0);
    PRE_MFMA_SYNC();
    MFMA_QUAD(1, 0);
    POST_MFMA_SYNC();

    // ---- phase 4: (mq1, nq1) — af reused; per-tile counted vmcnt ----
    ds_bfrags(&Bs[buf][1][0], wn, lane, bfr);
    stageB(k + 2, 0);
    if (k >= KT - 2) asm volatile("s_waitcnt vmcnt(0)" ::: "memory");
    else             asm volatile("s_waitcnt vmcnt(4)" ::: "memory");
    PRE_MFMA_SYNC();
    MFMA_QUAD(1, 1);
    POST_MFMA_SYNC();
  }

  // ---- epilogue: C write (rows mq*128+wr*64+m*16, cols nq*128+wn*32+n*16) ----
#pragma unroll
  for (int mi = 0; mi < 8; ++mi) {
    const int mq = mi >> 2, m = mi & 3;
#pragma unroll
    for (int ni = 0; ni < 4; ++ni) {
      const int nq = ni >> 1, n = ni & 1;
#pragma unroll
      for (int r = 0; r < 4; ++r) {
        size_t row = arow0 + mq * 128 + wr * 64 + m * 16 + ((lane >> 4) << 2) + r;
        size_t col = (size_t)tc * 256 + nq * 128 + wn * 32 + n * 16 + (lane & 15);
        float v = acc[mi][ni][r];
        if constexpr (__is_same(OutT, float)) {
          C[row * N + col] = v;
        } else {
          C[row * N + col] = f2bf(v);
        }
      }
    }
  }
}

// ---------------- Flash attention (causal), bf16 QKV -> bf16 O ----------------
// v2: double-buffered K/V, ONE barrier per kv-tile, prefetch issued before compute,
// V reg->LDS writes after compute (issue-early/write-late), longest blocks first,
// setprio around MFMA clusters.
__global__ __launch_bounds__(256) void attn_kernel(const u16* __restrict__ Q,
                                                   const u16* __restrict__ K,
                                                   const u16* __restrict__ V,
                                                   u16* __restrict__ O) {
  __shared__ u16 Ks[2][64 * 128];   // [kv][d], chunk-XOR swizzled
  __shared__ u16 Vt[2][128 * 64];   // [d][kv], chunk-XOR swizzled
  __shared__ u16 Ps[4][32 * 64];    // per-wave P

  const int blk = blockIdx.x;
  const int qt = 15 - (blk >> 6);   // longest-running q-tiles launch first
  const int bh = blk & 63;
  const int b = bh >> 5, h = bh & 31;
  const int q0 = qt << 7;
  const int tid = threadIdx.x, lane = tid & 63, w = tid >> 6;
  const int wq0 = q0 + w * 32;

  bf16x8 qf[2][4];
#pragma unroll
  for (int m = 0; m < 2; ++m)
#pragma unroll
    for (int kk = 0; kk < 4; ++kk) {
      int row = wq0 + m * 16 + (lane & 15);
      int k = kk * 32 + ((lane >> 4) << 3);
      qf[m][kk] = *reinterpret_cast<const bf16x8*>(Q + (size_t)(b * S_ + row) * D_ + h * HD_ + k);
    }

  f32x4 oacc[2][8] = {};
  float mrun[2][4], lrun[2][4];
#pragma unroll
  for (int m = 0; m < 2; ++m)
#pragma unroll
    for (int r = 0; r < 4; ++r) { mrun[m][r] = -__builtin_inff(); lrun[m][r] = 0.f; }

  const int ntiles = 2 * qt + 2;
  u16x8 vreg[4];

  {
    const int kv0 = 0;
#pragma unroll
    for (int it = 0; it < 4; ++it) {
      int ff = it * 256 + tid;
      int row = ff >> 4, cc = ff & 15;
      int scc = cc ^ (row & 7);
      GLD_TO_LDS16(K + (size_t)(b * S_ + kv0 + row) * D_ + h * HD_ + scc * 8, &Ks[0][ff << 3]);
    }
#pragma unroll
    for (int it = 0; it < 4; ++it) {
      int ff = it * 256 + tid;
      int r = ff & 63, dc = ff >> 6;
      vreg[it] = *reinterpret_cast<const u16x8*>(V + (size_t)(b * S_ + kv0 + r) * D_ + h * HD_ + dc * 8);
    }
#pragma unroll
    for (int it = 0; it < 4; ++it) {
      int ff = it * 256 + tid;
      int r = ff & 63, dc = ff >> 6;
#pragma unroll
      for (int j = 0; j < 8; ++j) {
        int d = dc * 8 + j;
        Vt[0][(d << 6) + (((r >> 3) ^ (d & 7)) << 3) + (r & 7)] = vreg[it][j];
      }
    }
  }
  __syncthreads();

  for (int t = 0; t < ntiles; ++t) {
    const int cur = t & 1, nxt = cur ^ 1;
    const bool pre = (t + 1 < ntiles);
    if (pre) {
      const int kv1 = (t + 1) << 6;
#pragma unroll
      for (int it = 0; it < 4; ++it) {
        int ff = it * 256 + tid;
        int row = ff >> 4, cc = ff & 15;
        int scc = cc ^ (row & 7);
        GLD_TO_LDS16(K + (size_t)(b * S_ + kv1 + row) * D_ + h * HD_ + scc * 8, &Ks[nxt][ff << 3]);
      }
#pragma unroll
      for (int it = 0; it < 4; ++it) {
        int ff = it * 256 + tid;
        int r = ff & 63, dc = ff >> 6;
        vreg[it] = *reinterpret_cast<const u16x8*>(V + (size_t)(b * S_ + kv1 + r) * D_ + h * HD_ + dc * 8);
      }
    }

    const int kv0 = t << 6;
    if (kv0 <= wq0 + 31) {
      f32x4 s[2][4] = {};
      __builtin_amdgcn_s_setprio(1);
#pragma unroll
      for (int kk = 0; kk < 4; ++kk) {
        bf16x8 kf[4];
#pragma unroll
        for (int n = 0; n < 4; ++n) {
          int row = n * 16 + (lane & 15);
          int kc = kk * 4 + (lane >> 4);
          kf[n] = *reinterpret_cast<const bf16x8*>(&Ks[cur][(row << 7) + ((kc ^ (row & 7)) << 3)]);
        }
#pragma unroll
        for (int m = 0; m < 2; ++m)
#pragma unroll
          for (int n = 0; n < 4; ++n)
            s[m][n] = __builtin_amdgcn_mfma_f32_16x16x32_bf16(qf[m][kk], kf[n], s[m][n], 0, 0, 0);
      }
      __builtin_amdgcn_s_setprio(0);
      if (kv0 + 63 > wq0) {
#pragma unroll
        for (int m = 0; m < 2; ++m)
#pragma unroll
          for (int n = 0; n < 4; ++n)
#pragma unroll
            for (int r = 0; r < 4; ++r) {
              int rowg = wq0 + m * 16 + ((lane >> 4) << 2) + r;
              int colg = kv0 + n * 16 + (lane & 15);
              if (colg > rowg) s[m][n][r] = -1e30f;
            }
      }
#pragma unroll
      for (int m = 0; m < 2; ++m) {
        float psc[4];
#pragma unroll
        for (int r = 0; r < 4; ++r) {
          float vmax = fmaxf(fmaxf(s[m][0][r], s[m][1][r]), fmaxf(s[m][2][r], s[m][3][r]));
          vmax = fmaxf(vmax, __shfl_xor(vmax, 1));
          vmax = fmaxf(vmax, __shfl_xor(vmax, 2));
          vmax = fmaxf(vmax, __shfl_xor(vmax, 4));
          vmax = fmaxf(vmax, __shfl_xor(vmax, 8));
          float mnew = fmaxf(mrun[m][r], vmax);
          float sc = __expf((mrun[m][r] - mnew) * SM_SCALE);
          mrun[m][r] = mnew;
          float psum = 0.f;
#pragma unroll
          for (int n = 0; n < 4; ++n) {
            float p = __expf((s[m][n][r] - mnew) * SM_SCALE);
            s[m][n][r] = p;
            psum += p;
          }
          psum += __shfl_xor(psum, 1);
          psum += __shfl_xor(psum, 2);
          psum += __shfl_xor(psum, 4);
          psum += __shfl_xor(psum, 8);
          lrun[m][r] = lrun[m][r] * sc + psum;
          psc[r] = sc;
        }
#pragma unroll
        for (int n = 0; n < 8; ++n)
#pragma unroll
          for (int r = 0; r < 4; ++r) oacc[m][n][r] *= psc[r];
      }
      u16* P = Ps[w];
#pragma unroll
      for (int m = 0; m < 2; ++m)
#pragma unroll
        for (int n = 0; n < 4; ++n)
#pragma unroll
          for (int r = 0; r < 4; ++r) {
            int prow = m * 16 + ((lane >> 4) << 2) + r;
            int pcol = n * 16 + (lane & 15);
            P[(prow << 6) + (((pcol >> 3) ^ (prow & 7)) << 3) + (pcol & 7)] = f2bf(s[m][n][r]);
          }
      __builtin_amdgcn_s_setprio(1);
#pragma unroll
      for (int kk2 = 0; kk2 < 2; ++kk2) {
        bf16x8 pa[2];
#pragma unroll
        for (int m = 0; m < 2; ++m) {
          int prow = m * 16 + (lane & 15);
          int kc = kk2 * 4 + (lane >> 4);
          pa[m] = *reinterpret_cast<const bf16x8*>(&P[(prow << 6) + ((kc ^ (prow & 7)) << 3)]);
        }
#pragma unroll
        for (int n = 0; n < 8; ++n) {
          int vrow = n * 16 + (lane & 15);
          int kc = kk2 * 4 + (lane >> 4);
          bf16x8 vf = *reinterpret_cast<const bf16x8*>(&Vt[cur][(vrow << 6) + ((kc ^ (vrow & 7)) << 3)]);
#pragma unroll
          for (int m = 0; m < 2; ++m)
            oacc[m][n] = __builtin_amdgcn_mfma_f32_16x16x32_bf16(pa[m], vf, oacc[m][n], 0, 0, 0);
        }
      }
      __builtin_amdgcn_s_setprio(0);
    }

    if (pre) {
#pragma unroll
      for (int it = 0; it < 4; ++it) {
        int ff = it * 256 + tid;
        int r = ff & 63, dc = ff >> 6;
#pragma unroll
        for (int j = 0; j < 8; ++j) {
          int d = dc * 8 + j;
          Vt[nxt][(d << 6) + (((r >> 3) ^ (d & 7)) << 3) + (r & 7)] = vreg[it][j];
        }
      }
    }
    __syncthreads();
  }

#pragma unroll
  for (int m = 0; m < 2; ++m)
#pragma unroll
    for (int n = 0; n < 8; ++n)
#pragma unroll
      for (int r = 0; r < 4; ++r) {
        int rowg = wq0 + m * 16 + ((lane >> 4) << 2) + r;
        int colg = n * 16 + (lane & 15);
        float v = oacc[m][n][r] / lrun[m][r];
        O[(size_t)(b * S_ + rowg) * D_ + h * HD_ + colg] = f2bf(v);
      }
}

// ---------------- launcher ----------------
extern "C" void kernel_launch(void* const* d_in, const int* in_sizes, int n_in,
                              void* d_out, int out_size, void* d_ws, size_t ws_size,
                              hipStream_t stream) {
  const float* x = (const float*)d_in[0];
  const float* wq = (const float*)d_in[1];
  const float* wk = (const float*)d_in[2];
  const float* wv = (const float*)d_in[3];
  const float* wo = (const float*)d_in[4];
  const float* fc = (const float*)d_in[5];
  const float* fs = (const float*)d_in[6];
  float* out = (float*)d_out;

  const size_t SLOT = (size_t)B_ * S_ * D_;  // 16,777,216 elements
  u16* ws = (u16*)d_ws;
  u16* wqb = ws + 0 * SLOT;
  u16* wkb = ws + 1 * SLOT;
  u16* wvb = ws + 2 * SLOT;
  u16* wob = ws + 3 * SLOT;
  u16* xb  = ws + 4 * SLOT;  // reused as attention output O after QKV GEMMs
  u16* Qb  = ws + 5 * SLOT;
  u16* Kb  = ws + 6 * SLOT;
  u16* Vb  = ws + 7 * SLOT;
  u16* Ob  = xb;

  const int n4 = (int)(SLOT / 4);
  cvt_kernel<<<2048, 256, 0, stream>>>(x, xb, n4);
  cvt_kernel<<<2048, 256, 0, stream>>>(wq, wqb, n4);
  cvt_kernel<<<2048, 256, 0, stream>>>(wk, wkb, n4);
  cvt_kernel<<<2048, 256, 0, stream>>>(wv, wvb, n4);
  cvt_kernel<<<2048, 256, 0, stream>>>(wo, wob, n4);

  gemm256_kernel<u16><<<256, 512, 0, stream>>>(xb, wqb, Qb, B_ * S_, D_, D_);
  gemm256_kernel<u16><<<256, 512, 0, stream>>>(xb, wkb, Kb, B_ * S_, D_, D_);
  gemm256_kernel<u16><<<256, 512, 0, stream>>>(xb, wvb, Vb, B_ * S_, D_, D_);

  rope_kernel<<<2048, 256, 0, stream>>>(Qb, fc, fs);
  rope_kernel<<<2048, 256, 0, stream>>>(Kb, fc, fs);

  attn_kernel<<<1024, 256, 0, stream>>>(Qb, Kb, Vb, Ob);

  gemm256_kernel<float><<<256, 512, 0, stream>>>(Ob, wob, out, B_ * S_, D_, D_);
}

// Round 6
// 816.036 us; speedup vs baseline: 1.7362x; 1.2445x over previous
//
#include <hip/hip_runtime.h>

typedef __bf16 bf16x8 __attribute__((ext_vector_type(8)));
typedef float f32x4 __attribute__((ext_vector_type(4)));
typedef float f32x16 __attribute__((ext_vector_type(16)));
typedef unsigned short u16;
typedef unsigned int u32;
typedef u16 u16x8 __attribute__((ext_vector_type(8)));
typedef u16 u16x4 __attribute__((ext_vector_type(4)));
typedef u32 u32x4 __attribute__((ext_vector_type(4)));

#define B_ 2
#define S_ 2048
#define D_ 4096
#define H_ 32
#define HD_ 128
#define SM_SCALE 0.08838834764831845f   // 1/sqrt(128)
#define C2_ 0.12751743f                 // SM_SCALE * log2(e)

__device__ __forceinline__ u16 f2bf(float f) {
  __bf16 h = (__bf16)f;
  return __builtin_bit_cast(unsigned short, h);
}
__device__ __forceinline__ float bf2f(u16 u) {
  return (float)__builtin_bit_cast(__bf16, u);
}

// async global->LDS, 16B per lane. LDS dest must be wave-uniform base + lane*16.
#define GLD_TO_LDS16(gsrc, ldst)                                                     \
  __builtin_amdgcn_global_load_lds((__attribute__((address_space(1))) void*)(gsrc),  \
                                   (__attribute__((address_space(3))) void*)(ldst),  \
                                   16, 0, 0)

// ---------------- fp32 -> bf16 conversion ----------------
__global__ __launch_bounds__(256) void cvt_kernel(const float* __restrict__ src,
                                                  u16* __restrict__ dst, int n4) {
  int i = blockIdx.x * blockDim.x + threadIdx.x;
  int stride = gridDim.x * blockDim.x;
  for (; i < n4; i += stride) {
    float4 v = reinterpret_cast<const float4*>(src)[i];
    u16x4 o;
    o[0] = f2bf(v.x); o[1] = f2bf(v.y); o[2] = f2bf(v.z); o[3] = f2bf(v.w);
    reinterpret_cast<u16x4*>(dst)[i] = o;
  }
}

// ---------------- RoPE (in place on bf16 (B*S, D) tensor) ----------------
__global__ __launch_bounds__(256) void rope_kernel(u16* __restrict__ T,
                                                   const float* __restrict__ fc,
                                                   const float* __restrict__ fs) {
  const int n = B_ * S_ * D_ / 2;  // pairs
  int i = blockIdx.x * blockDim.x + threadIdx.x;
  int stride = gridDim.x * blockDim.x;
  unsigned int* Tp = reinterpret_cast<unsigned int*>(T);
  for (; i < n; i += stride) {
    int row = i >> 11;       // D/2 = 2048 pairs per row
    int pr = i & 2047;       // pair-in-row = h*64 + p
    int s = row & (S_ - 1);
    int p = pr & 63;
    float c = fc[(s << 6) + p];
    float sn = fs[(s << 6) + p];
    unsigned int u = Tp[i];  // pair offset in uints == i
    float xr = bf2f((u16)(u & 0xffff));
    float xi = bf2f((u16)(u >> 16));
    float orr = xr * c - xi * sn;
    float oii = xr * sn + xi * c;
    Tp[i] = (unsigned int)f2bf(orr) | ((unsigned int)f2bf(oii) << 16);
  }
}

// ---------------- GEMM v4: m201-style 256^2 8-phase schedule ----------------
__device__ __forceinline__ void ds_afrags(const u16* half_base, int wr, int lane,
                                          bf16x8 af[2][4]) {
#pragma unroll
  for (int ks = 0; ks < 2; ++ks)
#pragma unroll
    for (int m = 0; m < 4; ++m) {
      int rr = wr * 64 + m * 16 + (lane & 15);
      int c8 = (ks * 4 + (lane >> 4)) ^ (rr & 7);
      af[ks][m] = *reinterpret_cast<const bf16x8*>(half_base + rr * 64 + c8 * 8);
    }
}
__device__ __forceinline__ void ds_bfrags(const u16* half_base, int wn, int lane,
                                          bf16x8 bfr[2][2]) {
#pragma unroll
  for (int ks = 0; ks < 2; ++ks)
#pragma unroll
    for (int n = 0; n < 2; ++n) {
      int rr = wn * 32 + n * 16 + (lane & 15);
      int c8 = (ks * 4 + (lane >> 4)) ^ (rr & 7);
      bfr[ks][n] = *reinterpret_cast<const bf16x8*>(half_base + rr * 64 + c8 * 8);
    }
}

#define MFMA_QUAD(MQ, NQ)                                                        \
  do {                                                                           \
    __builtin_amdgcn_s_setprio(1);                                               \
    _Pragma("unroll") for (int ks = 0; ks < 2; ++ks)                             \
      _Pragma("unroll") for (int m = 0; m < 4; ++m)                              \
        _Pragma("unroll") for (int n = 0; n < 2; ++n)                            \
          acc[(MQ) * 4 + m][(NQ) * 2 + n] =                                      \
              __builtin_amdgcn_mfma_f32_16x16x32_bf16(                           \
                  af[ks][m], bfr[ks][n], acc[(MQ) * 4 + m][(NQ) * 2 + n], 0, 0, 0); \
    __builtin_amdgcn_s_setprio(0);                                               \
  } while (0)

#define PRE_MFMA_SYNC()                                   \
  do {                                                    \
    __builtin_amdgcn_s_barrier();                         \
    asm volatile("s_waitcnt lgkmcnt(0)" ::: "memory");    \
    __builtin_amdgcn_sched_barrier(0);                    \
  } while (0)

#define POST_MFMA_SYNC()                                  \
  do {                                                    \
    __builtin_amdgcn_s_barrier();                         \
    __builtin_amdgcn_sched_barrier(0);                    \
  } while (0)

template <typename OutT>
__global__ __launch_bounds__(512, 2) void gemm256_kernel(const u16* __restrict__ A,
                                                         const u16* __restrict__ Bw,
                                                         OutT* __restrict__ C,
                                                         int M, int N, int K) {
  __shared__ u16 As[2][2][8192];  // [dbuf][half][r*64 + c]
  __shared__ u16 Bs[2][2][8192];
  const int tid = threadIdx.x;
  const int lane = tid & 63;
  const int w = tid >> 6;   // 0..7
  const int wr = w >> 2;    // 0..1
  const int wn = w & 3;     // 0..3
  const int nbx = N >> 8;
  const int nwg = (M >> 8) * nbx;
  int wg = blockIdx.x;
  if ((nwg & 7) == 0) wg = (wg & 7) * (nwg >> 3) + (wg >> 3);  // XCD swizzle
  const int tr = wg / nbx, tc = wg % nbx;

  const size_t arow0 = (size_t)tr * 256;
  const size_t brow0 = (size_t)tc * 256;
  const int KT = K >> 6;

  auto stageA = [&](int t, int half) {
    if (t >= KT) return;
    const int k0 = t << 6;
    u16* base = &As[t & 1][half][0];
#pragma unroll
    for (int i = 0; i < 2; ++i) {
      int q = i * 512 + tid;
      int r = q >> 3;
      int c8 = (q & 7) ^ (r & 7);
      GLD_TO_LDS16(A + (arow0 + half * 128 + r) * K + k0 + c8 * 8, base + q * 8);
    }
  };
  auto stageB = [&](int t, int half) {
    if (t >= KT) return;
    const int k0 = t << 6;
    u16* base = &Bs[t & 1][half][0];
#pragma unroll
    for (int i = 0; i < 2; ++i) {
      int q = i * 512 + tid;
      int r = q >> 3;
      int c8 = (q & 7) ^ (r & 7);
      GLD_TO_LDS16(Bw + (brow0 + half * 128 + r) * K + k0 + c8 * 8, base + q * 8);
    }
  };

  f32x4 acc[8][4] = {};

  // ---- prologue: tile0 (4 half-tiles) + tile1's A-h0, B-h0 ----
  stageA(0, 0); stageB(0, 0); stageA(0, 1); stageB(0, 1);
  stageA(1, 0); stageB(1, 0);
  asm volatile("s_waitcnt vmcnt(4)" ::: "memory");  // tile0 landed; tile1 h0s in flight
  __builtin_amdgcn_s_barrier();
  __builtin_amdgcn_sched_barrier(0);

  for (int k = 0; k < KT; ++k) {
    const int buf = k & 1;
    bf16x8 af[2][4], bfr[2][2];

    // ---- phase 1: (mq0, nq0) ----
    ds_afrags(&As[buf][0][0], wr, lane, af);
    ds_bfrags(&Bs[buf][0][0], wn, lane, bfr);
    stageA(k + 1, 1);
    PRE_MFMA_SYNC();
    MFMA_QUAD(0, 0);
    POST_MFMA_SYNC();

    // ---- phase 2: (mq0, nq1) — af reused ----
    ds_bfrags(&Bs[buf][1][0], wn, lane, bfr);
    stageB(k + 1, 1);
    PRE_MFMA_SYNC();
    MFMA_QUAD(0, 1);
    POST_MFMA_SYNC();

    // ---- phase 3: (mq1, nq0) ----
    ds_afrags(&As[buf][1][0], wr, lane, af);
    ds_bfrags(&Bs[buf][0][0], wn, lane, bfr);
    stageA(k + 2, 0);
    PRE_MFMA_SYNC();
    MFMA_QUAD(1, 0);
    POST_MFMA_SYNC();

    // ---- phase 4: (mq1, nq1) — af reused; per-tile counted vmcnt ----
    ds_bfrags(&Bs[buf][1][0], wn, lane, bfr);
    stageB(k + 2, 0);
    if (k >= KT - 2) asm volatile("s_waitcnt vmcnt(0)" ::: "memory");
    else             asm volatile("s_waitcnt vmcnt(4)" ::: "memory");
    PRE_MFMA_SYNC();
    MFMA_QUAD(1, 1);
    POST_MFMA_SYNC();
  }

  // ---- epilogue ----
#pragma unroll
  for (int mi = 0; mi < 8; ++mi) {
    const int mq = mi >> 2, m = mi & 3;
#pragma unroll
    for (int ni = 0; ni < 4; ++ni) {
      const int nq = ni >> 1, n = ni & 1;
#pragma unroll
      for (int r = 0; r < 4; ++r) {
        size_t row = arow0 + mq * 128 + wr * 64 + m * 16 + ((lane >> 4) << 2) + r;
        size_t col = (size_t)tc * 256 + nq * 128 + wn * 32 + n * 16 + (lane & 15);
        float v = acc[mi][ni][r];
        if constexpr (__is_same(OutT, float)) {
          C[row * N + col] = v;
        } else {
          C[row * N + col] = f2bf(v);
        }
      }
    }
  }
}

// ---------------- Flash attention v3 (causal), swapped-operand 32x32 MFMA ----------------
// Each lane owns ONE q row (col of S^T): softmax is lane-local + one shfl_xor(32).
// QK^T: S^T = mfma_32x32x16(K_frag, Q_frag) per kv-half x 8 k-steps.
// P -> bf16 in-register (v_cvt_pk_bf16_f32) + half-exchange (shfl_xor 32 + cndmask)
// builds PV B-frags; PV: O^T = mfma(V^T_frag from Vt LDS, P_frag). No P LDS.
// LDS: K,V double-buffered = 64 KB -> 2 blocks/CU.
__global__ __launch_bounds__(256, 2) void attn_kernel(const u16* __restrict__ Q,
                                                      const u16* __restrict__ K,
                                                      const u16* __restrict__ V,
                                                      u16* __restrict__ O) {
  __shared__ u16 Ks[2][64 * 128];   // [kv][d], chunk-XOR swizzled (cc ^= row&7)
  __shared__ u16 Vt[2][128 * 64];   // [d][kv], chunk-XOR swizzled (kvchunk ^= d&7)

  const int blk = blockIdx.x;
  const int qt = 15 - (blk >> 6);   // longest-running q-tiles launch first
  const int bh = blk & 63;
  const int b = bh >> 5, h = bh & 31;
  const int q0 = qt << 7;
  const int tid = threadIdx.x, lane = tid & 63, w = tid >> 6;
  const int wq0 = q0 + w * 32;
  const int l31 = lane & 31;
  const int hi = lane >> 5;               // 0/1 k-half
  const int qg = wq0 + l31;               // this lane's q row

  // Q frags: qf[kb][j] = Q[qg][kb*16 + hi*8 + j]  (B-operand layout, col=q)
  bf16x8 qf[8];
#pragma unroll
  for (int kb = 0; kb < 8; ++kb)
    qf[kb] = *reinterpret_cast<const bf16x8*>(Q + (size_t)(b * S_ + qg) * D_ + h * HD_ + kb * 16 + hi * 8);

  f32x16 oacc[4] = {};   // O^T[dblock]: col=q(lane), row=d
  float mrun = -__builtin_inff(), lrun = 0.f;

  const int ntiles = 2 * qt + 2;
  u16x8 vreg[4];

  // ---- prologue: stage tile 0 into buffer 0 ----
  {
#pragma unroll
    for (int it = 0; it < 4; ++it) {
      int ff = it * 256 + tid;
      int row = ff >> 4, cc = ff & 15;
      int scc = cc ^ (row & 7);
      GLD_TO_LDS16(K + (size_t)(b * S_ + row) * D_ + h * HD_ + scc * 8, &Ks[0][ff << 3]);
    }
#pragma unroll
    for (int it = 0; it < 4; ++it) {
      int ff = it * 256 + tid;
      int r = ff & 63, dc = ff >> 6;
      vreg[it] = *reinterpret_cast<const u16x8*>(V + (size_t)(b * S_ + r) * D_ + h * HD_ + dc * 8);
    }
#pragma unroll
    for (int it = 0; it < 4; ++it) {
      int ff = it * 256 + tid;
      int r = ff & 63, dc = ff >> 6;
#pragma unroll
      for (int j = 0; j < 8; ++j) {
        int d = dc * 8 + j;
        Vt[0][(d << 6) + (((r >> 3) ^ (d & 7)) << 3) + (r & 7)] = vreg[it][j];
      }
    }
  }
  __syncthreads();

  for (int t = 0; t < ntiles; ++t) {
    const int cur = t & 1, nxt = cur ^ 1;
    const bool pre = (t + 1 < ntiles);
    // ---- issue prefetch for tile t+1 (no waits here) ----
    if (pre) {
      const int kv1 = (t + 1) << 6;
#pragma unroll
      for (int it = 0; it < 4; ++it) {
        int ff = it * 256 + tid;
        int row = ff >> 4, cc = ff & 15;
        int scc = cc ^ (row & 7);
        GLD_TO_LDS16(K + (size_t)(b * S_ + kv1 + row) * D_ + h * HD_ + scc * 8, &Ks[nxt][ff << 3]);
      }
#pragma unroll
      for (int it = 0; it < 4; ++it) {
        int ff = it * 256 + tid;
        int r = ff & 63, dc = ff >> 6;
        vreg[it] = *reinterpret_cast<const u16x8*>(V + (size_t)(b * S_ + kv1 + r) * D_ + h * HD_ + dc * 8);
      }
    }

    const int kv0 = t << 6;
    if (kv0 <= wq0 + 31) {  // wave-uniform causal skip
      // ---- S^T = K Q^T : per kv-half (32 kv) x 8 k-steps ----
      f32x16 st[2] = {};
      __builtin_amdgcn_s_setprio(1);
#pragma unroll
      for (int kvh = 0; kvh < 2; ++kvh) {
#pragma unroll
        for (int kb = 0; kb < 8; ++kb) {
          int row = kvh * 32 + l31;
          int cc = (2 * kb + hi) ^ (row & 7);
          bf16x8 kf = *reinterpret_cast<const bf16x8*>(&Ks[cur][(row << 7) + (cc << 3)]);
          st[kvh] = __builtin_amdgcn_mfma_f32_32x32x16_bf16(kf, qf[kb], st[kvh], 0, 0, 0);
        }
      }
      __builtin_amdgcn_s_setprio(0);

      // ---- causal mask (diagonal tiles only). reg r -> kv = (r&3)+8*(r>>2)+4*hi ----
      if (kv0 + 63 > wq0) {
#pragma unroll
        for (int kvh = 0; kvh < 2; ++kvh)
#pragma unroll
          for (int r = 0; r < 16; ++r) {
            int kvg = kv0 + kvh * 32 + (r & 3) + 8 * (r >> 2) + 4 * hi;
            if (kvg > qg) st[kvh][r] = -1e30f;
          }
      }

      // ---- online softmax: lane-local row + one cross-half exchange ----
      float vmax = -1e30f;
#pragma unroll
      for (int kvh = 0; kvh < 2; ++kvh)
#pragma unroll
        for (int r = 0; r < 16; ++r) vmax = fmaxf(vmax, st[kvh][r]);
      vmax = fmaxf(vmax, __shfl_xor(vmax, 32));
      float mnew = fmaxf(mrun, vmax);
      float sc = exp2f((mrun - mnew) * C2_);
      mrun = mnew;
      float psum = 0.f;
#pragma unroll
      for (int kvh = 0; kvh < 2; ++kvh)
#pragma unroll
        for (int r = 0; r < 16; ++r) {
          float p = exp2f((st[kvh][r] - mnew) * C2_);
          st[kvh][r] = p;
          psum += p;
        }
      psum += __shfl_xor(psum, 32);
      lrun = lrun * sc + psum;
#pragma unroll
      for (int db = 0; db < 4; ++db)
#pragma unroll
        for (int r = 0; r < 16; ++r) oacc[db][r] *= sc;

      // ---- PV: O^T += V^T P^T, P packed in-register ----
      __builtin_amdgcn_s_setprio(1);
#pragma unroll
      for (int h2 = 0; h2 < 2; ++h2)
#pragma unroll
        for (int s2 = 0; s2 < 2; ++s2) {
          const int rb = s2 * 8;
          u32 w0, w1, w2, w3;
          asm("v_cvt_pk_bf16_f32 %0, %1, %2" : "=v"(w0) : "v"(st[h2][rb + 0]), "v"(st[h2][rb + 1]));
          asm("v_cvt_pk_bf16_f32 %0, %1, %2" : "=v"(w1) : "v"(st[h2][rb + 2]), "v"(st[h2][rb + 3]));
          asm("v_cvt_pk_bf16_f32 %0, %1, %2" : "=v"(w2) : "v"(st[h2][rb + 4]), "v"(st[h2][rb + 5]));
          asm("v_cvt_pk_bf16_f32 %0, %1, %2" : "=v"(w3) : "v"(st[h2][rb + 6]), "v"(st[h2][rb + 7]));
          u32 sw0 = (u32)__shfl_xor((int)w0, 32);
          u32 sw1 = (u32)__shfl_xor((int)w1, 32);
          u32 sw2 = (u32)__shfl_xor((int)w2, 32);
          u32 sw3 = (u32)__shfl_xor((int)w3, 32);
          u32x4 fw;
          fw[0] = hi ? sw2 : w0;
          fw[1] = hi ? sw3 : w1;
          fw[2] = hi ? w2 : sw0;
          fw[3] = hi ? w3 : sw1;
          bf16x8 pfrag = __builtin_bit_cast(bf16x8, fw);
#pragma unroll
          for (int db = 0; db < 4; ++db) {
            int d = db * 32 + l31;
            int cc = (h2 * 4 + s2 * 2 + hi) ^ (d & 7);
            bf16x8 va = *reinterpret_cast<const bf16x8*>(&Vt[cur][(d << 6) + (cc << 3)]);
            oacc[db] = __builtin_amdgcn_mfma_f32_32x32x16_bf16(va, pfrag, oacc[db], 0, 0, 0);
          }
        }
      __builtin_amdgcn_s_setprio(0);
    }

    // ---- late V write for tile t+1 ----
    if (pre) {
#pragma unroll
      for (int it = 0; it < 4; ++it) {
        int ff = it * 256 + tid;
        int r = ff & 63, dc = ff >> 6;
#pragma unroll
        for (int j = 0; j < 8; ++j) {
          int d = dc * 8 + j;
          Vt[nxt][(d << 6) + (((r >> 3) ^ (d & 7)) << 3) + (r & 7)] = vreg[it][j];
        }
      }
    }
    __syncthreads();  // single barrier per tile
  }

  // ---- epilogue: O[q][d] = oacc^T / lrun, u16x4 packed stores ----
  const float rinv = 1.0f / lrun;
#pragma unroll
  for (int db = 0; db < 4; ++db)
#pragma unroll
    for (int g = 0; g < 4; ++g) {
      u16x4 o4;
#pragma unroll
      for (int j = 0; j < 4; ++j) o4[j] = f2bf(oacc[db][g * 4 + j] * rinv);
      int d = db * 32 + g * 8 + 4 * hi;
      *reinterpret_cast<u16x4*>(O + (size_t)(b * S_ + qg) * D_ + h * HD_ + d) = o4;
    }
}

// ---------------- launcher ----------------
extern "C" void kernel_launch(void* const* d_in, const int* in_sizes, int n_in,
                              void* d_out, int out_size, void* d_ws, size_t ws_size,
                              hipStream_t stream) {
  const float* x = (const float*)d_in[0];
  const float* wq = (const float*)d_in[1];
  const float* wk = (const float*)d_in[2];
  const float* wv = (const float*)d_in[3];
  const float* wo = (const float*)d_in[4];
  const float* fc = (const float*)d_in[5];
  const float* fs = (const float*)d_in[6];
  float* out = (float*)d_out;

  const size_t SLOT = (size_t)B_ * S_ * D_;  // 16,777,216 elements
  u16* ws = (u16*)d_ws;
  u16* wqb = ws + 0 * SLOT;
  u16* wkb = ws + 1 * SLOT;
  u16* wvb = ws + 2 * SLOT;
  u16* wob = ws + 3 * SLOT;
  u16* xb  = ws + 4 * SLOT;  // reused as attention output O after QKV GEMMs
  u16* Qb  = ws + 5 * SLOT;
  u16* Kb  = ws + 6 * SLOT;
  u16* Vb  = ws + 7 * SLOT;
  u16* Ob  = xb;

  const int n4 = (int)(SLOT / 4);
  cvt_kernel<<<2048, 256, 0, stream>>>(x, xb, n4);
  cvt_kernel<<<2048, 256, 0, stream>>>(wq, wqb, n4);
  cvt_kernel<<<2048, 256, 0, stream>>>(wk, wkb, n4);
  cvt_kernel<<<2048, 256, 0, stream>>>(wv, wvb, n4);
  cvt_kernel<<<2048, 256, 0, stream>>>(wo, wob, n4);

  gemm256_kernel<u16><<<256, 512, 0, stream>>>(xb, wqb, Qb, B_ * S_, D_, D_);
  gemm256_kernel<u16><<<256, 512, 0, stream>>>(xb, wkb, Kb, B_ * S_, D_, D_);
  gemm256_kernel<u16><<<256, 512, 0, stream>>>(xb, wvb, Vb, B_ * S_, D_, D_);

  rope_kernel<<<2048, 256, 0, stream>>>(Qb, fc, fs);
  rope_kernel<<<2048, 256, 0, stream>>>(Kb, fc, fs);

  attn_kernel<<<1024, 256, 0, stream>>>(Qb, Kb, Vb, Ob);

  gemm256_kernel<float><<<256, 512, 0, stream>>>(Ob, wob, out, B_ * S_, D_, D_);
}

// Round 8
// 709.510 us; speedup vs baseline: 1.9969x; 1.1501x over previous
//
#include <hip/hip_runtime.h>

typedef __bf16 bf16x8 __attribute__((ext_vector_type(8)));
typedef float f32x4 __attribute__((ext_vector_type(4)));
typedef float f32x16 __attribute__((ext_vector_type(16)));
typedef unsigned short u16;
typedef unsigned int u32;
typedef u16 u16x8 __attribute__((ext_vector_type(8)));
typedef u16 u16x4 __attribute__((ext_vector_type(4)));
typedef u32 u32x4 __attribute__((ext_vector_type(4)));

#define B_ 2
#define S_ 2048
#define D_ 4096
#define H_ 32
#define HD_ 128
#define SM_SCALE 0.08838834764831845f   // 1/sqrt(128)
#define C2_ 0.12751743f                 // SM_SCALE * log2(e)

__device__ __forceinline__ u16 f2bf(float f) {
  __bf16 h = (__bf16)f;
  return __builtin_bit_cast(unsigned short, h);
}
__device__ __forceinline__ float bf2f(u16 u) {
  return (float)__builtin_bit_cast(__bf16, u);
}

// async global->LDS, 16B per lane. LDS dest must be wave-uniform base + lane*16.
#define GLD_TO_LDS16(gsrc, ldst)                                                     \
  __builtin_amdgcn_global_load_lds((__attribute__((address_space(1))) void*)(gsrc),  \
                                   (__attribute__((address_space(3))) void*)(ldst),  \
                                   16, 0, 0)

// ---------------- fp32 -> bf16 conversion ----------------
__global__ __launch_bounds__(256) void cvt_kernel(const float* __restrict__ src,
                                                  u16* __restrict__ dst, int n4) {
  int i = blockIdx.x * blockDim.x + threadIdx.x;
  int stride = gridDim.x * blockDim.x;
  for (; i < n4; i += stride) {
    float4 v = reinterpret_cast<const float4*>(src)[i];
    u16x4 o;
    o[0] = f2bf(v.x); o[1] = f2bf(v.y); o[2] = f2bf(v.z); o[3] = f2bf(v.w);
    reinterpret_cast<u16x4*>(dst)[i] = o;
  }
}

// ---------------- RoPE (in place on bf16 (B*S, D) tensor) ----------------
__global__ __launch_bounds__(256) void rope_kernel(u16* __restrict__ T,
                                                   const float* __restrict__ fc,
                                                   const float* __restrict__ fs) {
  const int n = B_ * S_ * D_ / 2;  // pairs
  int i = blockIdx.x * blockDim.x + threadIdx.x;
  int stride = gridDim.x * blockDim.x;
  unsigned int* Tp = reinterpret_cast<unsigned int*>(T);
  for (; i < n; i += stride) {
    int row = i >> 11;       // D/2 = 2048 pairs per row
    int pr = i & 2047;       // pair-in-row = h*64 + p
    int s = row & (S_ - 1);
    int p = pr & 63;
    float c = fc[(s << 6) + p];
    float sn = fs[(s << 6) + p];
    unsigned int u = Tp[i];  // pair offset in uints == i
    float xr = bf2f((u16)(u & 0xffff));
    float xi = bf2f((u16)(u >> 16));
    float orr = xr * c - xi * sn;
    float oii = xr * sn + xi * c;
    Tp[i] = (unsigned int)f2bf(orr) | ((unsigned int)f2bf(oii) << 16);
  }
}

// ---------------- GEMM v6b: 256^2, register-ping-pong 8-half-phase pipeline --------
// C[M,N] = A[M,K]*B[N,K]^T. 512 thr = 8 waves (2M x 4N), per-wave 128x64 out.
// BK=64, LDS 2dbuf x 2half x [128][64] x {A,B} = 128 KB. Phase order
// P1(0,0) P2(1,0) P3(1,1) P4(0,1); each phase = 2 half-phases of 8 MFMA; every
// ds_read fill drains UNDER an 8-MFMA cluster. Staging coverage (each half once):
//   A(t,0) <- P1 of iter t-1 (1-ahead: A-h0 is read EARLY at prev-P4 buf-cross fill)
//   A(t,1) <- P4 of iter t-2;  B(t,0) <- P2 of iter t-2;  B(t,1) <- P3 of iter t-2
//   prologue covers t=0 (all) and t=1 {B0,B1,A1}; P1 of iter 0 covers A(1,0).
//   (v6 BUG fixed: prologue staged A(1,0) twice and A(1,1) never.)
// vmcnt ledger (2 ops/stage): steady P4 outstanding =
//   [B(k+1,1),A(k+1,1),A(k+1,0),B(k+2,0),B(k+2,1),A(k+2,1)] = 12; vmcnt(4) drains
//   oldest 8 => tile k+1 fully in LDS; leaves [B(k+2,1),A(k+2,1)].
// Swizzle: chunk c8 ^= (row&7), applied at gl_lds SOURCE and ds_read (rule 21).

#define LGKM0()                                            \
  do {                                                     \
    asm volatile("s_waitcnt lgkmcnt(0)" ::: "memory");     \
    __builtin_amdgcn_sched_barrier(0);                     \
  } while (0)

__device__ __forceinline__ void fill_af(bf16x8 (&dst)[4], const u16* half_base,
                                        int wr, int lane, int ks) {
#pragma unroll
  for (int m = 0; m < 4; ++m) {
    int rr = wr * 64 + m * 16 + (lane & 15);
    int c8 = (ks * 4 + (lane >> 4)) ^ (rr & 7);
    dst[m] = *reinterpret_cast<const bf16x8*>(half_base + rr * 64 + c8 * 8);
  }
}
__device__ __forceinline__ void fill_bf(bf16x8 (&dst)[2][2], const u16* half_base,
                                        int wn, int lane) {
#pragma unroll
  for (int ks = 0; ks < 2; ++ks)
#pragma unroll
    for (int n = 0; n < 2; ++n) {
      int rr = wn * 32 + n * 16 + (lane & 15);
      int c8 = (ks * 4 + (lane >> 4)) ^ (rr & 7);
      dst[ks][n] = *reinterpret_cast<const bf16x8*>(half_base + rr * 64 + c8 * 8);
    }
}

#define MFMA8(MQ, NQ, KS, AF, BF)                                                \
  do {                                                                           \
    __builtin_amdgcn_s_setprio(1);                                               \
    _Pragma("unroll") for (int m = 0; m < 4; ++m)                                \
      _Pragma("unroll") for (int n = 0; n < 2; ++n)                              \
        acc[(MQ) * 4 + m][(NQ) * 2 + n] =                                        \
            __builtin_amdgcn_mfma_f32_16x16x32_bf16(                             \
                (AF)[m], (BF)[KS][n], acc[(MQ) * 4 + m][(NQ) * 2 + n], 0, 0, 0); \
    __builtin_amdgcn_s_setprio(0);                                               \
  } while (0)

template <typename OutT>
__global__ __launch_bounds__(512, 2) void gemm256_kernel(const u16* __restrict__ A,
                                                         const u16* __restrict__ Bw,
                                                         OutT* __restrict__ C,
                                                         int M, int N, int K) {
  __shared__ u16 As[2][2][8192];  // [dbuf][half][r*64 + c]
  __shared__ u16 Bs[2][2][8192];
  const int tid = threadIdx.x;
  const int lane = tid & 63;
  const int w = tid >> 6;   // 0..7
  const int wr = w >> 2;    // 0..1
  const int wn = w & 3;     // 0..3
  const int nbx = N >> 8;
  const int nby = M >> 8;
  const int nwg = nby * nbx;
  int tr, tc;
  if (nby == 16 && nbx == 16) {
    // 4x8 rectangular chunk per XCD: better L2 temporal sharing, less over-fetch
    int xcd = blockIdx.x & 7, j = blockIdx.x >> 3;
    tr = (xcd >> 1) * 4 + (j >> 3);
    tc = (xcd & 1) * 8 + (j & 7);
  } else {
    int wg = blockIdx.x;
    if ((nwg & 7) == 0) wg = (wg & 7) * (nwg >> 3) + (wg >> 3);
    tr = wg / nbx; tc = wg % nbx;
  }

  const size_t arow0 = (size_t)tr * 256;
  const size_t brow0 = (size_t)tc * 256;
  const int KT = K >> 6;

  auto stageA = [&](int t, int half) {
    if (t >= KT) return;
    const int k0 = t << 6;
    u16* base = &As[t & 1][half][0];
#pragma unroll
    for (int i = 0; i < 2; ++i) {
      int q = i * 512 + tid;
      int r = q >> 3;
      int c8 = (q & 7) ^ (r & 7);
      GLD_TO_LDS16(A + (arow0 + half * 128 + r) * K + k0 + c8 * 8, base + q * 8);
    }
  };
  auto stageB = [&](int t, int half) {
    if (t >= KT) return;
    const int k0 = t << 6;
    u16* base = &Bs[t & 1][half][0];
#pragma unroll
    for (int i = 0; i < 2; ++i) {
      int q = i * 512 + tid;
      int r = q >> 3;
      int c8 = (q & 7) ^ (r & 7);
      GLD_TO_LDS16(Bw + (brow0 + half * 128 + r) * K + k0 + c8 * 8, base + q * 8);
    }
  };

  f32x4 acc[8][4] = {};
  bf16x8 afX[4], afY[4], bf0[2][2], bf1[2][2];

  // ---- prologue: tile0 all 4 halves + tile1 {Bh0, Bh1, Ah1} (A(1,0) comes from
  // P1 of iter 0 — the 1-ahead slot). 14 ops; vmcnt(4) drains tile0 + B(1,0).
  stageA(0, 0); stageA(0, 1); stageB(0, 0); stageB(0, 1);
  stageB(1, 0); stageB(1, 1); stageA(1, 1);
  asm volatile("s_waitcnt vmcnt(4)" ::: "memory");  // tile0 landed; {B(1,1),A(1,1)} in flight
  __builtin_amdgcn_s_barrier();
  __builtin_amdgcn_sched_barrier(0);
  fill_af(afX, &As[0][0][0], wr, lane, 0);  // A0 ks0
  fill_bf(bf0, &Bs[0][0][0], wn, lane);     // B0 both ks

  for (int k = 0; k < KT; ++k) {
    const int buf = k & 1, nb = buf ^ 1;
    const u16* A0 = &As[buf][0][0];
    const u16* A1 = &As[buf][1][0];
    const u16* B1L = &Bs[buf][1][0];
    const u16* A0n = &As[nb][0][0];
    const u16* B0n = &Bs[nb][0][0];

    // ---- P1 (mq0,nq0) ----
    LGKM0();                                  // drains afX, bf0 (prev P4 fills)
    fill_af(afY, A0, wr, lane, 1);
    fill_bf(bf1, B1L, wn, lane);
    stageA(k + 1, 0);
    MFMA8(0, 0, 0, afX, bf0);
    LGKM0();                                  // afY, bf1
    fill_af(afX, A1, wr, lane, 0);            // for P2h0
    MFMA8(0, 0, 1, afY, bf0);
    __builtin_amdgcn_s_barrier();

    // ---- P2 (mq1,nq0) ----
    LGKM0();                                  // afX
    fill_af(afY, A1, wr, lane, 1);
    stageB(k + 2, 0);
    MFMA8(1, 0, 0, afX, bf0);
    LGKM0();                                  // afY
    fill_af(afX, A1, wr, lane, 0);            // re-read for P3h0
    MFMA8(1, 0, 1, afY, bf0);
    __builtin_amdgcn_s_barrier();

    // ---- P3 (mq1,nq1) ----
    LGKM0();                                  // afX
    fill_af(afY, A1, wr, lane, 1);            // re-read
    stageB(k + 2, 1);
    MFMA8(1, 1, 0, afX, bf1);
    LGKM0();                                  // afY
    fill_af(afX, A0, wr, lane, 0);            // re-read for P4h0
    MFMA8(1, 1, 1, afY, bf1);
    __builtin_amdgcn_s_barrier();

    // ---- P4 (mq0,nq1) ----
    LGKM0();                                  // afX
    fill_af(afY, A0, wr, lane, 1);            // re-read
    MFMA8(0, 1, 0, afX, bf1);
    LGKM0();                                  // afY
    stageA(k + 2, 1);
    if (k >= KT - 3) asm volatile("s_waitcnt vmcnt(0)" ::: "memory");
    else             asm volatile("s_waitcnt vmcnt(4)" ::: "memory");
    __builtin_amdgcn_s_barrier();             // all waves' tile-(k+1) loads landed
    __builtin_amdgcn_sched_barrier(0);
    if (k + 1 < KT) {                         // buf-crossing fills, hidden under h1
      fill_af(afX, A0n, wr, lane, 0);
      fill_bf(bf0, B0n, wn, lane);
    }
    MFMA8(0, 1, 1, afY, bf1);
    __builtin_amdgcn_s_barrier();             // phase boundary (protects P1 stage)
  }

  // ---- epilogue ----
#pragma unroll
  for (int mi = 0; mi < 8; ++mi) {
    const int mq = mi >> 2, m = mi & 3;
#pragma unroll
    for (int ni = 0; ni < 4; ++ni) {
      const int nq = ni >> 1, n = ni & 1;
#pragma unroll
      for (int r = 0; r < 4; ++r) {
        size_t row = arow0 + mq * 128 + wr * 64 + m * 16 + ((lane >> 4) << 2) + r;
        size_t col = (size_t)tc * 256 + nq * 128 + wn * 32 + n * 16 + (lane & 15);
        float v = acc[mi][ni][r];
        if constexpr (__is_same(OutT, float)) {
          C[row * N + col] = v;
        } else {
          C[row * N + col] = f2bf(v);
        }
      }
    }
  }
}

// ---------------- Flash attention v3 (causal), swapped-operand 32x32 MFMA ----------------
__global__ __launch_bounds__(256, 2) void attn_kernel(const u16* __restrict__ Q,
                                                      const u16* __restrict__ K,
                                                      const u16* __restrict__ V,
                                                      u16* __restrict__ O) {
  __shared__ u16 Ks[2][64 * 128];   // [kv][d], chunk-XOR swizzled (cc ^= row&7)
  __shared__ u16 Vt[2][128 * 64];   // [d][kv], chunk-XOR swizzled (kvchunk ^= d&7)

  const int blk = blockIdx.x;
  const int qt = 15 - (blk >> 6);   // longest-running q-tiles launch first
  const int bh = blk & 63;
  const int b = bh >> 5, h = bh & 31;
  const int q0 = qt << 7;
  const int tid = threadIdx.x, lane = tid & 63, w = tid >> 6;
  const int wq0 = q0 + w * 32;
  const int l31 = lane & 31;
  const int hi = lane >> 5;               // 0/1 k-half
  const int qg = wq0 + l31;               // this lane's q row

  bf16x8 qf[8];
#pragma unroll
  for (int kb = 0; kb < 8; ++kb)
    qf[kb] = *reinterpret_cast<const bf16x8*>(Q + (size_t)(b * S_ + qg) * D_ + h * HD_ + kb * 16 + hi * 8);

  f32x16 oacc[4] = {};   // O^T[dblock]: col=q(lane), row=d
  float mrun = -__builtin_inff(), lrun = 0.f;

  const int ntiles = 2 * qt + 2;
  u16x8 vreg[4];

  {
#pragma unroll
    for (int it = 0; it < 4; ++it) {
      int ff = it * 256 + tid;
      int row = ff >> 4, cc = ff & 15;
      int scc = cc ^ (row & 7);
      GLD_TO_LDS16(K + (size_t)(b * S_ + row) * D_ + h * HD_ + scc * 8, &Ks[0][ff << 3]);
    }
#pragma unroll
    for (int it = 0; it < 4; ++it) {
      int ff = it * 256 + tid;
      int r = ff & 63, dc = ff >> 6;
      vreg[it] = *reinterpret_cast<const u16x8*>(V + (size_t)(b * S_ + r) * D_ + h * HD_ + dc * 8);
    }
#pragma unroll
    for (int it = 0; it < 4; ++it) {
      int ff = it * 256 + tid;
      int r = ff & 63, dc = ff >> 6;
#pragma unroll
      for (int j = 0; j < 8; ++j) {
        int d = dc * 8 + j;
        Vt[0][(d << 6) + (((r >> 3) ^ (d & 7)) << 3) + (r & 7)] = vreg[it][j];
      }
    }
  }
  __syncthreads();

  for (int t = 0; t < ntiles; ++t) {
    const int cur = t & 1, nxt = cur ^ 1;
    const bool pre = (t + 1 < ntiles);
    if (pre) {
      const int kv1 = (t + 1) << 6;
#pragma unroll
      for (int it = 0; it < 4; ++it) {
        int ff = it * 256 + tid;
        int row = ff >> 4, cc = ff & 15;
        int scc = cc ^ (row & 7);
        GLD_TO_LDS16(K + (size_t)(b * S_ + kv1 + row) * D_ + h * HD_ + scc * 8, &Ks[nxt][ff << 3]);
      }
#pragma unroll
      for (int it = 0; it < 4; ++it) {
        int ff = it * 256 + tid;
        int r = ff & 63, dc = ff >> 6;
        vreg[it] = *reinterpret_cast<const u16x8*>(V + (size_t)(b * S_ + kv1 + r) * D_ + h * HD_ + dc * 8);
      }
    }

    const int kv0 = t << 6;
    if (kv0 <= wq0 + 31) {  // wave-uniform causal skip
      f32x16 st[2] = {};
      __builtin_amdgcn_s_setprio(1);
#pragma unroll
      for (int kvh = 0; kvh < 2; ++kvh) {
#pragma unroll
        for (int kb = 0; kb < 8; ++kb) {
          int row = kvh * 32 + l31;
          int cc = (2 * kb + hi) ^ (row & 7);
          bf16x8 kf = *reinterpret_cast<const bf16x8*>(&Ks[cur][(row << 7) + (cc << 3)]);
          st[kvh] = __builtin_amdgcn_mfma_f32_32x32x16_bf16(kf, qf[kb], st[kvh], 0, 0, 0);
        }
      }
      __builtin_amdgcn_s_setprio(0);

      if (kv0 + 63 > wq0) {
#pragma unroll
        for (int kvh = 0; kvh < 2; ++kvh)
#pragma unroll
          for (int r = 0; r < 16; ++r) {
            int kvg = kv0 + kvh * 32 + (r & 3) + 8 * (r >> 2) + 4 * hi;
            if (kvg > qg) st[kvh][r] = -1e30f;
          }
      }

      float vmax = -1e30f;
#pragma unroll
      for (int kvh = 0; kvh < 2; ++kvh)
#pragma unroll
        for (int r = 0; r < 16; ++r) vmax = fmaxf(vmax, st[kvh][r]);
      vmax = fmaxf(vmax, __shfl_xor(vmax, 32));
      float mnew = fmaxf(mrun, vmax);
      float sc = exp2f((mrun - mnew) * C2_);
      mrun = mnew;
      float psum = 0.f;
#pragma unroll
      for (int kvh = 0; kvh < 2; ++kvh)
#pragma unroll
        for (int r = 0; r < 16; ++r) {
          float p = exp2f((st[kvh][r] - mnew) * C2_);
          st[kvh][r] = p;
          psum += p;
        }
      psum += __shfl_xor(psum, 32);
      lrun = lrun * sc + psum;
#pragma unroll
      for (int db = 0; db < 4; ++db)
#pragma unroll
        for (int r = 0; r < 16; ++r) oacc[db][r] *= sc;

      __builtin_amdgcn_s_setprio(1);
#pragma unroll
      for (int h2 = 0; h2 < 2; ++h2)
#pragma unroll
        for (int s2 = 0; s2 < 2; ++s2) {
          const int rb = s2 * 8;
          u32 w0, w1, w2, w3;
          asm("v_cvt_pk_bf16_f32 %0, %1, %2" : "=v"(w0) : "v"(st[h2][rb + 0]), "v"(st[h2][rb + 1]));
          asm("v_cvt_pk_bf16_f32 %0, %1, %2" : "=v"(w1) : "v"(st[h2][rb + 2]), "v"(st[h2][rb + 3]));
          asm("v_cvt_pk_bf16_f32 %0, %1, %2" : "=v"(w2) : "v"(st[h2][rb + 4]), "v"(st[h2][rb + 5]));
          asm("v_cvt_pk_bf16_f32 %0, %1, %2" : "=v"(w3) : "v"(st[h2][rb + 6]), "v"(st[h2][rb + 7]));
          u32 sw0 = (u32)__shfl_xor((int)w0, 32);
          u32 sw1 = (u32)__shfl_xor((int)w1, 32);
          u32 sw2 = (u32)__shfl_xor((int)w2, 32);
          u32 sw3 = (u32)__shfl_xor((int)w3, 32);
          u32x4 fw;
          fw[0] = hi ? sw2 : w0;
          fw[1] = hi ? sw3 : w1;
          fw[2] = hi ? w2 : sw0;
          fw[3] = hi ? w3 : sw1;
          bf16x8 pfrag = __builtin_bit_cast(bf16x8, fw);
#pragma unroll
          for (int db = 0; db < 4; ++db) {
            int d = db * 32 + l31;
            int cc = (h2 * 4 + s2 * 2 + hi) ^ (d & 7);
            bf16x8 va = *reinterpret_cast<const bf16x8*>(&Vt[cur][(d << 6) + (cc << 3)]);
            oacc[db] = __builtin_amdgcn_mfma_f32_32x32x16_bf16(va, pfrag, oacc[db], 0, 0, 0);
          }
        }
      __builtin_amdgcn_s_setprio(0);
    }

    if (pre) {
#pragma unroll
      for (int it = 0; it < 4; ++it) {
        int ff = it * 256 + tid;
        int r = ff & 63, dc = ff >> 6;
#pragma unroll
        for (int j = 0; j < 8; ++j) {
          int d = dc * 8 + j;
          Vt[nxt][(d << 6) + (((r >> 3) ^ (d & 7)) << 3) + (r & 7)] = vreg[it][j];
        }
      }
    }
    __syncthreads();
  }

  const float rinv = 1.0f / lrun;
#pragma unroll
  for (int db = 0; db < 4; ++db)
#pragma unroll
    for (int g = 0; g < 4; ++g) {
      u16x4 o4;
#pragma unroll
      for (int j = 0; j < 4; ++j) o4[j] = f2bf(oacc[db][g * 4 + j] * rinv);
      int d = db * 32 + g * 8 + 4 * hi;
      *reinterpret_cast<u16x4*>(O + (size_t)(b * S_ + qg) * D_ + h * HD_ + d) = o4;
    }
}

// ---------------- launcher ----------------
extern "C" void kernel_launch(void* const* d_in, const int* in_sizes, int n_in,
                              void* d_out, int out_size, void* d_ws, size_t ws_size,
                              hipStream_t stream) {
  const float* x = (const float*)d_in[0];
  const float* wq = (const float*)d_in[1];
  const float* wk = (const float*)d_in[2];
  const float* wv = (const float*)d_in[3];
  const float* wo = (const float*)d_in[4];
  const float* fc = (const float*)d_in[5];
  const float* fs = (const float*)d_in[6];
  float* out = (float*)d_out;

  const size_t SLOT = (size_t)B_ * S_ * D_;  // 16,777,216 elements
  u16* ws = (u16*)d_ws;
  u16* wqb = ws + 0 * SLOT;
  u16* wkb = ws + 1 * SLOT;
  u16* wvb = ws + 2 * SLOT;
  u16* wob = ws + 3 * SLOT;
  u16* xb  = ws + 4 * SLOT;  // reused as attention output O after QKV GEMMs
  u16* Qb  = ws + 5 * SLOT;
  u16* Kb  = ws + 6 * SLOT;
  u16* Vb  = ws + 7 * SLOT;
  u16* Ob  = xb;

  const int n4 = (int)(SLOT / 4);
  cvt_kernel<<<2048, 256, 0, stream>>>(x, xb, n4);
  cvt_kernel<<<2048, 256, 0, stream>>>(wq, wqb, n4);
  cvt_kernel<<<2048, 256, 0, stream>>>(wk, wkb, n4);
  cvt_kernel<<<2048, 256, 0, stream>>>(wv, wvb, n4);
  cvt_kernel<<<2048, 256, 0, stream>>>(wo, wob, n4);

  gemm256_kernel<u16><<<256, 512, 0, stream>>>(xb, wqb, Qb, B_ * S_, D_, D_);
  gemm256_kernel<u16><<<256, 512, 0, stream>>>(xb, wkb, Kb, B_ * S_, D_, D_);
  gemm256_kernel<u16><<<256, 512, 0, stream>>>(xb, wvb, Vb, B_ * S_, D_, D_);

  rope_kernel<<<2048, 256, 0, stream>>>(Qb, fc, fs);
  rope_kernel<<<2048, 256, 0, stream>>>(Kb, fc, fs);

  attn_kernel<<<1024, 256, 0, stream>>>(Qb, Kb, Vb, Ob);

  gemm256_kernel<float><<<256, 512, 0, stream>>>(Ob, wob, out, B_ * S_, D_, D_);
}

// Round 9
// 680.429 us; speedup vs baseline: 2.0822x; 1.0427x over previous
//
#include <hip/hip_runtime.h>

typedef __bf16 bf16x8 __attribute__((ext_vector_type(8)));
typedef float f32x4 __attribute__((ext_vector_type(4)));
typedef float f32x16 __attribute__((ext_vector_type(16)));
typedef unsigned short u16;
typedef unsigned int u32;
typedef u16 u16x8 __attribute__((ext_vector_type(8)));
typedef u16 u16x4 __attribute__((ext_vector_type(4)));
typedef u32 u32x4 __attribute__((ext_vector_type(4)));

#define B_ 2
#define S_ 2048
#define D_ 4096
#define H_ 32
#define HD_ 128
#define SM_SCALE 0.08838834764831845f   // 1/sqrt(128)
#define C2_ 0.12751743f                 // SM_SCALE * log2(e)

__device__ __forceinline__ u16 f2bf(float f) {
  __bf16 h = (__bf16)f;
  return __builtin_bit_cast(unsigned short, h);
}
__device__ __forceinline__ float bf2f(u16 u) {
  return (float)__builtin_bit_cast(__bf16, u);
}

// async global->LDS, 16B per lane. LDS dest must be wave-uniform base + lane*16.
#define GLD_TO_LDS16(gsrc, ldst)                                                     \
  __builtin_amdgcn_global_load_lds((__attribute__((address_space(1))) void*)(gsrc),  \
                                   (__attribute__((address_space(3))) void*)(ldst),  \
                                   16, 0, 0)

// ---------------- fp32 -> bf16 conversion, 5 tensors in one launch ----------------
__global__ __launch_bounds__(256) void cvt5_kernel(const float* __restrict__ s0,
                                                   const float* __restrict__ s1,
                                                   const float* __restrict__ s2,
                                                   const float* __restrict__ s3,
                                                   const float* __restrict__ s4,
                                                   u16* __restrict__ d0,
                                                   u16* __restrict__ d1,
                                                   u16* __restrict__ d2,
                                                   u16* __restrict__ d3,
                                                   u16* __restrict__ d4,
                                                   int n4) {
  const int region = blockIdx.x >> 9;           // 512 blocks per tensor
  const float* src = region == 0 ? s0 : region == 1 ? s1 : region == 2 ? s2
                   : region == 3 ? s3 : s4;
  u16* dst = region == 0 ? d0 : region == 1 ? d1 : region == 2 ? d2
           : region == 3 ? d3 : d4;
  int i = (blockIdx.x & 511) * 256 + threadIdx.x;
  const int stride = 512 * 256;
  for (; i < n4; i += stride) {
    float4 v = reinterpret_cast<const float4*>(src)[i];
    u16x4 o;
    o[0] = f2bf(v.x); o[1] = f2bf(v.y); o[2] = f2bf(v.z); o[3] = f2bf(v.w);
    reinterpret_cast<u16x4*>(dst)[i] = o;
  }
}

// ---------------- GEMM v7: 256^2 register-ping-pong pipeline, optional fused RoPE ----
// Structure identical to v6b (verified r8). ROPE=true (Q/K projections): epilogue
// applies rotation pre-rounding. Pair (col,col^1) = (lane,lane^1), same row;
// v' = v*c -/+ o*s (even/odd lane), o = shfl_xor(v,1); tables fc/fs[s][64].

#define LGKM0()                                            \
  do {                                                     \
    asm volatile("s_waitcnt lgkmcnt(0)" ::: "memory");     \
    __builtin_amdgcn_sched_barrier(0);                     \
  } while (0)

__device__ __forceinline__ void fill_af(bf16x8 (&dst)[4], const u16* half_base,
                                        int wr, int lane, int ks) {
#pragma unroll
  for (int m = 0; m < 4; ++m) {
    int rr = wr * 64 + m * 16 + (lane & 15);
    int c8 = (ks * 4 + (lane >> 4)) ^ (rr & 7);
    dst[m] = *reinterpret_cast<const bf16x8*>(half_base + rr * 64 + c8 * 8);
  }
}
__device__ __forceinline__ void fill_bf(bf16x8 (&dst)[2][2], const u16* half_base,
                                        int wn, int lane) {
#pragma unroll
  for (int ks = 0; ks < 2; ++ks)
#pragma unroll
    for (int n = 0; n < 2; ++n) {
      int rr = wn * 32 + n * 16 + (lane & 15);
      int c8 = (ks * 4 + (lane >> 4)) ^ (rr & 7);
      dst[ks][n] = *reinterpret_cast<const bf16x8*>(half_base + rr * 64 + c8 * 8);
    }
}

#define MFMA8(MQ, NQ, KS, AF, BF)                                                \
  do {                                                                           \
    __builtin_amdgcn_s_setprio(1);                                               \
    _Pragma("unroll") for (int m = 0; m < 4; ++m)                                \
      _Pragma("unroll") for (int n = 0; n < 2; ++n)                              \
        acc[(MQ) * 4 + m][(NQ) * 2 + n] =                                        \
            __builtin_amdgcn_mfma_f32_16x16x32_bf16(                             \
                (AF)[m], (BF)[KS][n], acc[(MQ) * 4 + m][(NQ) * 2 + n], 0, 0, 0); \
    __builtin_amdgcn_s_setprio(0);                                               \
  } while (0)

template <typename OutT, bool ROPE>
__global__ __launch_bounds__(512, 2) void gemm256_kernel(const u16* __restrict__ A,
                                                         const u16* __restrict__ Bw,
                                                         OutT* __restrict__ C,
                                                         int M, int N, int K,
                                                         const float* __restrict__ fc,
                                                         const float* __restrict__ fs) {
  __shared__ u16 As[2][2][8192];  // [dbuf][half][r*64 + c]
  __shared__ u16 Bs[2][2][8192];
  const int tid = threadIdx.x;
  const int lane = tid & 63;
  const int w = tid >> 6;   // 0..7
  const int wr = w >> 2;    // 0..1
  const int wn = w & 3;     // 0..3
  const int nbx = N >> 8;
  const int nby = M >> 8;
  const int nwg = nby * nbx;
  int tr, tc;
  if (nby == 16 && nbx == 16) {
    // 4x8 rectangular chunk per XCD: better L2 temporal sharing, less over-fetch
    int xcd = blockIdx.x & 7, j = blockIdx.x >> 3;
    tr = (xcd >> 1) * 4 + (j >> 3);
    tc = (xcd & 1) * 8 + (j & 7);
  } else {
    int wg = blockIdx.x;
    if ((nwg & 7) == 0) wg = (wg & 7) * (nwg >> 3) + (wg >> 3);
    tr = wg / nbx; tc = wg % nbx;
  }

  const size_t arow0 = (size_t)tr * 256;
  const size_t brow0 = (size_t)tc * 256;
  const int KT = K >> 6;

  auto stageA = [&](int t, int half) {
    if (t >= KT) return;
    const int k0 = t << 6;
    u16* base = &As[t & 1][half][0];
#pragma unroll
    for (int i = 0; i < 2; ++i) {
      int q = i * 512 + tid;
      int r = q >> 3;
      int c8 = (q & 7) ^ (r & 7);
      GLD_TO_LDS16(A + (arow0 + half * 128 + r) * K + k0 + c8 * 8, base + q * 8);
    }
  };
  auto stageB = [&](int t, int half) {
    if (t >= KT) return;
    const int k0 = t << 6;
    u16* base = &Bs[t & 1][half][0];
#pragma unroll
    for (int i = 0; i < 2; ++i) {
      int q = i * 512 + tid;
      int r = q >> 3;
      int c8 = (q & 7) ^ (r & 7);
      GLD_TO_LDS16(Bw + (brow0 + half * 128 + r) * K + k0 + c8 * 8, base + q * 8);
    }
  };

  f32x4 acc[8][4] = {};
  bf16x8 afX[4], afY[4], bf0[2][2], bf1[2][2];

  // ---- prologue: tile0 all 4 halves + tile1 {Bh0, Bh1, Ah1}; A(1,0) from P1 of
  // iter 0. 14 ops; vmcnt(4) drains tile0 + B(1,0), leaves {B(1,1),A(1,1)}.
  stageA(0, 0); stageA(0, 1); stageB(0, 0); stageB(0, 1);
  stageB(1, 0); stageB(1, 1); stageA(1, 1);
  asm volatile("s_waitcnt vmcnt(4)" ::: "memory");
  __builtin_amdgcn_s_barrier();
  __builtin_amdgcn_sched_barrier(0);
  fill_af(afX, &As[0][0][0], wr, lane, 0);  // A0 ks0
  fill_bf(bf0, &Bs[0][0][0], wn, lane);     // B0 both ks

  for (int k = 0; k < KT; ++k) {
    const int buf = k & 1, nb = buf ^ 1;
    const u16* A0 = &As[buf][0][0];
    const u16* A1 = &As[buf][1][0];
    const u16* B1L = &Bs[buf][1][0];
    const u16* A0n = &As[nb][0][0];
    const u16* B0n = &Bs[nb][0][0];

    // ---- P1 (mq0,nq0) ----
    LGKM0();                                  // drains afX, bf0 (prev P4 fills)
    fill_af(afY, A0, wr, lane, 1);
    fill_bf(bf1, B1L, wn, lane);
    stageA(k + 1, 0);
    MFMA8(0, 0, 0, afX, bf0);
    LGKM0();                                  // afY, bf1
    fill_af(afX, A1, wr, lane, 0);            // for P2h0
    MFMA8(0, 0, 1, afY, bf0);
    __builtin_amdgcn_s_barrier();

    // ---- P2 (mq1,nq0) ----
    LGKM0();                                  // afX
    fill_af(afY, A1, wr, lane, 1);
    stageB(k + 2, 0);
    MFMA8(1, 0, 0, afX, bf0);
    LGKM0();                                  // afY
    fill_af(afX, A1, wr, lane, 0);            // re-read for P3h0
    MFMA8(1, 0, 1, afY, bf0);
    __builtin_amdgcn_s_barrier();

    // ---- P3 (mq1,nq1) ----
    LGKM0();                                  // afX
    fill_af(afY, A1, wr, lane, 1);            // re-read
    stageB(k + 2, 1);
    MFMA8(1, 1, 0, afX, bf1);
    LGKM0();                                  // afY
    fill_af(afX, A0, wr, lane, 0);            // re-read for P4h0
    MFMA8(1, 1, 1, afY, bf1);
    __builtin_amdgcn_s_barrier();

    // ---- P4 (mq0,nq1) ----
    LGKM0();                                  // afX
    fill_af(afY, A0, wr, lane, 1);            // re-read
    MFMA8(0, 1, 0, afX, bf1);
    LGKM0();                                  // afY
    stageA(k + 2, 1);
    if (k >= KT - 3) asm volatile("s_waitcnt vmcnt(0)" ::: "memory");
    else             asm volatile("s_waitcnt vmcnt(4)" ::: "memory");
    __builtin_amdgcn_s_barrier();             // all waves' tile-(k+1) loads landed
    __builtin_amdgcn_sched_barrier(0);
    if (k + 1 < KT) {                         // buf-crossing fills, hidden under h1
      fill_af(afX, A0n, wr, lane, 0);
      fill_bf(bf0, B0n, wn, lane);
    }
    MFMA8(0, 1, 1, afY, bf1);
    __builtin_amdgcn_s_barrier();             // phase boundary (protects P1 stage)
  }

  // ---- epilogue (optional fused RoPE for Q/K projections) ----
#pragma unroll
  for (int mi = 0; mi < 8; ++mi) {
    const int mq = mi >> 2, m = mi & 3;
#pragma unroll
    for (int ni = 0; ni < 4; ++ni) {
      const int nq = ni >> 1, n = ni & 1;
#pragma unroll
      for (int r = 0; r < 4; ++r) {
        size_t row = arow0 + mq * 128 + wr * 64 + m * 16 + ((lane >> 4) << 2) + r;
        size_t col = (size_t)tc * 256 + nq * 128 + wn * 32 + n * 16 + (lane & 15);
        float v = acc[mi][ni][r];
        if constexpr (ROPE) {
          float o = __shfl_xor(v, 1);                       // partner (col^1), same row
          int s = (int)(row & (S_ - 1));
          int p = (wn * 32 + n * 16 + (lane & 14)) >> 1;    // (col&127)>>1
          float cv = fc[(s << 6) + p];
          float sv = fs[(s << 6) + p];
          v = (lane & 1) ? (v * cv + o * sv) : (v * cv - o * sv);
        }
        if constexpr (__is_same(OutT, float)) {
          C[row * N + col] = v;
        } else {
          C[row * N + col] = f2bf(v);
        }
      }
    }
  }
}

// ---------------- Flash attention v3b (causal), swapped-operand 32x32 MFMA ----------------
// v3 + defer-max (T13): skip O-rescale when the wave's row maxima grew < 64 raw
// (~5.66 scaled; P bounded by e^5.66≈287 — safe in bf16 P / fp32 sums).
__global__ __launch_bounds__(256, 2) void attn_kernel(const u16* __restrict__ Q,
                                                      const u16* __restrict__ K,
                                                      const u16* __restrict__ V,
                                                      u16* __restrict__ O) {
  __shared__ u16 Ks[2][64 * 128];   // [kv][d], chunk-XOR swizzled (cc ^= row&7)
  __shared__ u16 Vt[2][128 * 64];   // [d][kv], chunk-XOR swizzled (kvchunk ^= d&7)

  const int blk = blockIdx.x;
  const int qt = 15 - (blk >> 6);   // longest-running q-tiles launch first
  const int bh = blk & 63;
  const int b = bh >> 5, h = bh & 31;
  const int q0 = qt << 7;
  const int tid = threadIdx.x, lane = tid & 63, w = tid >> 6;
  const int wq0 = q0 + w * 32;
  const int l31 = lane & 31;
  const int hi = lane >> 5;               // 0/1 k-half
  const int qg = wq0 + l31;               // this lane's q row

  bf16x8 qf[8];
#pragma unroll
  for (int kb = 0; kb < 8; ++kb)
    qf[kb] = *reinterpret_cast<const bf16x8*>(Q + (size_t)(b * S_ + qg) * D_ + h * HD_ + kb * 16 + hi * 8);

  f32x16 oacc[4] = {};   // O^T[dblock]: col=q(lane), row=d
  float mrun = -__builtin_inff(), lrun = 0.f;

  const int ntiles = 2 * qt + 2;
  u16x8 vreg[4];

  {
#pragma unroll
    for (int it = 0; it < 4; ++it) {
      int ff = it * 256 + tid;
      int row = ff >> 4, cc = ff & 15;
      int scc = cc ^ (row & 7);
      GLD_TO_LDS16(K + (size_t)(b * S_ + row) * D_ + h * HD_ + scc * 8, &Ks[0][ff << 3]);
    }
#pragma unroll
    for (int it = 0; it < 4; ++it) {
      int ff = it * 256 + tid;
      int r = ff & 63, dc = ff >> 6;
      vreg[it] = *reinterpret_cast<const u16x8*>(V + (size_t)(b * S_ + r) * D_ + h * HD_ + dc * 8);
    }
#pragma unroll
    for (int it = 0; it < 4; ++it) {
      int ff = it * 256 + tid;
      int r = ff & 63, dc = ff >> 6;
#pragma unroll
      for (int j = 0; j < 8; ++j) {
        int d = dc * 8 + j;
        Vt[0][(d << 6) + (((r >> 3) ^ (d & 7)) << 3) + (r & 7)] = vreg[it][j];
      }
    }
  }
  __syncthreads();

  for (int t = 0; t < ntiles; ++t) {
    const int cur = t & 1, nxt = cur ^ 1;
    const bool pre = (t + 1 < ntiles);
    if (pre) {
      const int kv1 = (t + 1) << 6;
#pragma unroll
      for (int it = 0; it < 4; ++it) {
        int ff = it * 256 + tid;
        int row = ff >> 4, cc = ff & 15;
        int scc = cc ^ (row & 7);
        GLD_TO_LDS16(K + (size_t)(b * S_ + kv1 + row) * D_ + h * HD_ + scc * 8, &Ks[nxt][ff << 3]);
      }
#pragma unroll
      for (int it = 0; it < 4; ++it) {
        int ff = it * 256 + tid;
        int r = ff & 63, dc = ff >> 6;
        vreg[it] = *reinterpret_cast<const u16x8*>(V + (size_t)(b * S_ + kv1 + r) * D_ + h * HD_ + dc * 8);
      }
    }

    const int kv0 = t << 6;
    if (kv0 <= wq0 + 31) {  // wave-uniform causal skip
      f32x16 st[2] = {};
      __builtin_amdgcn_s_setprio(1);
#pragma unroll
      for (int kvh = 0; kvh < 2; ++kvh) {
#pragma unroll
        for (int kb = 0; kb < 8; ++kb) {
          int row = kvh * 32 + l31;
          int cc = (2 * kb + hi) ^ (row & 7);
          bf16x8 kf = *reinterpret_cast<const bf16x8*>(&Ks[cur][(row << 7) + (cc << 3)]);
          st[kvh] = __builtin_amdgcn_mfma_f32_32x32x16_bf16(kf, qf[kb], st[kvh], 0, 0, 0);
        }
      }
      __builtin_amdgcn_s_setprio(0);

      if (kv0 + 63 > wq0) {
#pragma unroll
        for (int kvh = 0; kvh < 2; ++kvh)
#pragma unroll
          for (int r = 0; r < 16; ++r) {
            int kvg = kv0 + kvh * 32 + (r & 3) + 8 * (r >> 2) + 4 * hi;
            if (kvg > qg) st[kvh][r] = -1e30f;
          }
      }

      float vmax = -1e30f;
#pragma unroll
      for (int kvh = 0; kvh < 2; ++kvh)
#pragma unroll
        for (int r = 0; r < 16; ++r) vmax = fmaxf(vmax, st[kvh][r]);
      vmax = fmaxf(vmax, __shfl_xor(vmax, 32));
      // defer-max: rescale only when some row's max grew by >64 raw (~5.66 scaled)
      if (!__all(vmax <= mrun + 64.0f)) {
        float mnew = fmaxf(mrun, vmax);
        float sc = exp2f((mrun - mnew) * C2_);
        mrun = mnew;
        lrun *= sc;
#pragma unroll
        for (int db = 0; db < 4; ++db)
#pragma unroll
          for (int r = 0; r < 16; ++r) oacc[db][r] *= sc;
      }
      float psum = 0.f;
#pragma unroll
      for (int kvh = 0; kvh < 2; ++kvh)
#pragma unroll
        for (int r = 0; r < 16; ++r) {
          float p = exp2f((st[kvh][r] - mrun) * C2_);
          st[kvh][r] = p;
          psum += p;
        }
      psum += __shfl_xor(psum, 32);
      lrun += psum;

      __builtin_amdgcn_s_setprio(1);
#pragma unroll
      for (int h2 = 0; h2 < 2; ++h2)
#pragma unroll
        for (int s2 = 0; s2 < 2; ++s2) {
          const int rb = s2 * 8;
          u32 w0, w1, w2, w3;
          asm("v_cvt_pk_bf16_f32 %0, %1, %2" : "=v"(w0) : "v"(st[h2][rb + 0]), "v"(st[h2][rb + 1]));
          asm("v_cvt_pk_bf16_f32 %0, %1, %2" : "=v"(w1) : "v"(st[h2][rb + 2]), "v"(st[h2][rb + 3]));
          asm("v_cvt_pk_bf16_f32 %0, %1, %2" : "=v"(w2) : "v"(st[h2][rb + 4]), "v"(st[h2][rb + 5]));
          asm("v_cvt_pk_bf16_f32 %0, %1, %2" : "=v"(w3) : "v"(st[h2][rb + 6]), "v"(st[h2][rb + 7]));
          u32 sw0 = (u32)__shfl_xor((int)w0, 32);
          u32 sw1 = (u32)__shfl_xor((int)w1, 32);
          u32 sw2 = (u32)__shfl_xor((int)w2, 32);
          u32 sw3 = (u32)__shfl_xor((int)w3, 32);
          u32x4 fw;
          fw[0] = hi ? sw2 : w0;
          fw[1] = hi ? sw3 : w1;
          fw[2] = hi ? w2 : sw0;
          fw[3] = hi ? w3 : sw1;
          bf16x8 pfrag = __builtin_bit_cast(bf16x8, fw);
#pragma unroll
          for (int db = 0; db < 4; ++db) {
            int d = db * 32 + l31;
            int cc = (h2 * 4 + s2 * 2 + hi) ^ (d & 7);
            bf16x8 va = *reinterpret_cast<const bf16x8*>(&Vt[cur][(d << 6) + (cc << 3)]);
            oacc[db] = __builtin_amdgcn_mfma_f32_32x32x16_bf16(va, pfrag, oacc[db], 0, 0, 0);
          }
        }
      __builtin_amdgcn_s_setprio(0);
    }

    if (pre) {
#pragma unroll
      for (int it = 0; it < 4; ++it) {
        int ff = it * 256 + tid;
        int r = ff & 63, dc = ff >> 6;
#pragma unroll
        for (int j = 0; j < 8; ++j) {
          int d = dc * 8 + j;
          Vt[nxt][(d << 6) + (((r >> 3) ^ (d & 7)) << 3) + (r & 7)] = vreg[it][j];
        }
      }
    }
    __syncthreads();
  }

  const float rinv = 1.0f / lrun;
#pragma unroll
  for (int db = 0; db < 4; ++db)
#pragma unroll
    for (int g = 0; g < 4; ++g) {
      u16x4 o4;
#pragma unroll
      for (int j = 0; j < 4; ++j) o4[j] = f2bf(oacc[db][g * 4 + j] * rinv);
      int d = db * 32 + g * 8 + 4 * hi;
      *reinterpret_cast<u16x4*>(O + (size_t)(b * S_ + qg) * D_ + h * HD_ + d) = o4;
    }
}

// ---------------- launcher ----------------
extern "C" void kernel_launch(void* const* d_in, const int* in_sizes, int n_in,
                              void* d_out, int out_size, void* d_ws, size_t ws_size,
                              hipStream_t stream) {
  const float* x = (const float*)d_in[0];
  const float* wq = (const float*)d_in[1];
  const float* wk = (const float*)d_in[2];
  const float* wv = (const float*)d_in[3];
  const float* wo = (const float*)d_in[4];
  const float* fc = (const float*)d_in[5];
  const float* fs = (const float*)d_in[6];
  float* out = (float*)d_out;

  const size_t SLOT = (size_t)B_ * S_ * D_;  // 16,777,216 elements
  u16* ws = (u16*)d_ws;
  u16* wqb = ws + 0 * SLOT;
  u16* wkb = ws + 1 * SLOT;
  u16* wvb = ws + 2 * SLOT;
  u16* wob = ws + 3 * SLOT;
  u16* xb  = ws + 4 * SLOT;  // reused as attention output O after QKV GEMMs
  u16* Qb  = ws + 5 * SLOT;
  u16* Kb  = ws + 6 * SLOT;
  u16* Vb  = ws + 7 * SLOT;
  u16* Ob  = xb;

  const int n4 = (int)(SLOT / 4);
  cvt5_kernel<<<2560, 256, 0, stream>>>(x, wq, wk, wv, wo, xb, wqb, wkb, wvb, wob, n4);

  gemm256_kernel<u16, true><<<256, 512, 0, stream>>>(xb, wqb, Qb, B_ * S_, D_, D_, fc, fs);
  gemm256_kernel<u16, true><<<256, 512, 0, stream>>>(xb, wkb, Kb, B_ * S_, D_, D_, fc, fs);
  gemm256_kernel<u16, false><<<256, 512, 0, stream>>>(xb, wvb, Vb, B_ * S_, D_, D_, fc, fs);

  attn_kernel<<<1024, 256, 0, stream>>>(Qb, Kb, Vb, Ob);

  gemm256_kernel<float, false><<<256, 512, 0, stream>>>(Ob, wob, out, B_ * S_, D_, D_, fc, fs);
}

// Round 10
// 680.239 us; speedup vs baseline: 2.0828x; 1.0003x over previous
//
#include <hip/hip_runtime.h>

typedef __bf16 bf16x8 __attribute__((ext_vector_type(8)));
typedef float f32x4 __attribute__((ext_vector_type(4)));
typedef float f32x16 __attribute__((ext_vector_type(16)));
typedef unsigned short u16;
typedef unsigned int u32;
typedef u16 u16x8 __attribute__((ext_vector_type(8)));
typedef u16 u16x4 __attribute__((ext_vector_type(4)));
typedef u32 u32x4 __attribute__((ext_vector_type(4)));

#define B_ 2
#define S_ 2048
#define D_ 4096
#define H_ 32
#define HD_ 128
#define SM_SCALE 0.08838834764831845f   // 1/sqrt(128)
#define C2_ 0.12751743f                 // SM_SCALE * log2(e)

__device__ __forceinline__ u16 f2bf(float f) {
  __bf16 h = (__bf16)f;
  return __builtin_bit_cast(unsigned short, h);
}
__device__ __forceinline__ float bf2f(u16 u) {
  return (float)__builtin_bit_cast(__bf16, u);
}

// async global->LDS, 16B per lane. LDS dest must be wave-uniform base + lane*16.
#define GLD_TO_LDS16(gsrc, ldst)                                                     \
  __builtin_amdgcn_global_load_lds((__attribute__((address_space(1))) void*)(gsrc),  \
                                   (__attribute__((address_space(3))) void*)(ldst),  \
                                   16, 0, 0)

// ---------------- fp32 -> bf16 conversion, 5 tensors in one launch ----------------
__global__ __launch_bounds__(256) void cvt5_kernel(const float* __restrict__ s0,
                                                   const float* __restrict__ s1,
                                                   const float* __restrict__ s2,
                                                   const float* __restrict__ s3,
                                                   const float* __restrict__ s4,
                                                   u16* __restrict__ d0,
                                                   u16* __restrict__ d1,
                                                   u16* __restrict__ d2,
                                                   u16* __restrict__ d3,
                                                   u16* __restrict__ d4,
                                                   int n4) {
  const int region = blockIdx.x >> 9;           // 512 blocks per tensor
  const float* src = region == 0 ? s0 : region == 1 ? s1 : region == 2 ? s2
                   : region == 3 ? s3 : s4;
  u16* dst = region == 0 ? d0 : region == 1 ? d1 : region == 2 ? d2
           : region == 3 ? d3 : d4;
  int i = (blockIdx.x & 511) * 256 + threadIdx.x;
  const int stride = 512 * 256;
  for (; i < n4; i += stride) {
    float4 v = reinterpret_cast<const float4*>(src)[i];
    u16x4 o;
    o[0] = f2bf(v.x); o[1] = f2bf(v.y); o[2] = f2bf(v.z); o[3] = f2bf(v.w);
    reinterpret_cast<u16x4*>(dst)[i] = o;
  }
}

// ---------------- GEMM v7: 256^2 register-ping-pong pipeline, optional fused RoPE ----
// Structure identical to v6b (verified r8). ROPE=true (Q/K projections): epilogue
// applies rotation pre-rounding. Pair (col,col^1) = (lane,lane^1), same row;
// v' = v*c -/+ o*s (even/odd lane), o = shfl_xor(v,1); tables fc/fs[s][64].

#define LGKM0()                                            \
  do {                                                     \
    asm volatile("s_waitcnt lgkmcnt(0)" ::: "memory");     \
    __builtin_amdgcn_sched_barrier(0);                     \
  } while (0)

__device__ __forceinline__ void fill_af(bf16x8 (&dst)[4], const u16* half_base,
                                        int wr, int lane, int ks) {
#pragma unroll
  for (int m = 0; m < 4; ++m) {
    int rr = wr * 64 + m * 16 + (lane & 15);
    int c8 = (ks * 4 + (lane >> 4)) ^ (rr & 7);
    dst[m] = *reinterpret_cast<const bf16x8*>(half_base + rr * 64 + c8 * 8);
  }
}
__device__ __forceinline__ void fill_bf(bf16x8 (&dst)[2][2], const u16* half_base,
                                        int wn, int lane) {
#pragma unroll
  for (int ks = 0; ks < 2; ++ks)
#pragma unroll
    for (int n = 0; n < 2; ++n) {
      int rr = wn * 32 + n * 16 + (lane & 15);
      int c8 = (ks * 4 + (lane >> 4)) ^ (rr & 7);
      dst[ks][n] = *reinterpret_cast<const bf16x8*>(half_base + rr * 64 + c8 * 8);
    }
}

#define MFMA8(MQ, NQ, KS, AF, BF)                                                \
  do {                                                                           \
    __builtin_amdgcn_s_setprio(1);                                               \
    _Pragma("unroll") for (int m = 0; m < 4; ++m)                                \
      _Pragma("unroll") for (int n = 0; n < 2; ++n)                              \
        acc[(MQ) * 4 + m][(NQ) * 2 + n] =                                        \
            __builtin_amdgcn_mfma_f32_16x16x32_bf16(                             \
                (AF)[m], (BF)[KS][n], acc[(MQ) * 4 + m][(NQ) * 2 + n], 0, 0, 0); \
    __builtin_amdgcn_s_setprio(0);                                               \
  } while (0)

template <typename OutT, bool ROPE>
__global__ __launch_bounds__(512, 2) void gemm256_kernel(const u16* __restrict__ A,
                                                         const u16* __restrict__ Bw,
                                                         OutT* __restrict__ C,
                                                         int M, int N, int K,
                                                         const float* __restrict__ fc,
                                                         const float* __restrict__ fs) {
  __shared__ u16 As[2][2][8192];  // [dbuf][half][r*64 + c]
  __shared__ u16 Bs[2][2][8192];
  const int tid = threadIdx.x;
  const int lane = tid & 63;
  const int w = tid >> 6;   // 0..7
  const int wr = w >> 2;    // 0..1
  const int wn = w & 3;     // 0..3
  const int nbx = N >> 8;
  const int nby = M >> 8;
  const int nwg = nby * nbx;
  int tr, tc;
  if (nby == 16 && nbx == 16) {
    // 4x8 rectangular chunk per XCD: better L2 temporal sharing, less over-fetch
    int xcd = blockIdx.x & 7, j = blockIdx.x >> 3;
    tr = (xcd >> 1) * 4 + (j >> 3);
    tc = (xcd & 1) * 8 + (j & 7);
  } else {
    int wg = blockIdx.x;
    if ((nwg & 7) == 0) wg = (wg & 7) * (nwg >> 3) + (wg >> 3);
    tr = wg / nbx; tc = wg % nbx;
  }

  const size_t arow0 = (size_t)tr * 256;
  const size_t brow0 = (size_t)tc * 256;
  const int KT = K >> 6;

  auto stageA = [&](int t, int half) {
    if (t >= KT) return;
    const int k0 = t << 6;
    u16* base = &As[t & 1][half][0];
#pragma unroll
    for (int i = 0; i < 2; ++i) {
      int q = i * 512 + tid;
      int r = q >> 3;
      int c8 = (q & 7) ^ (r & 7);
      GLD_TO_LDS16(A + (arow0 + half * 128 + r) * K + k0 + c8 * 8, base + q * 8);
    }
  };
  auto stageB = [&](int t, int half) {
    if (t >= KT) return;
    const int k0 = t << 6;
    u16* base = &Bs[t & 1][half][0];
#pragma unroll
    for (int i = 0; i < 2; ++i) {
      int q = i * 512 + tid;
      int r = q >> 3;
      int c8 = (q & 7) ^ (r & 7);
      GLD_TO_LDS16(Bw + (brow0 + half * 128 + r) * K + k0 + c8 * 8, base + q * 8);
    }
  };

  f32x4 acc[8][4] = {};
  bf16x8 afX[4], afY[4], bf0[2][2], bf1[2][2];

  // ---- prologue: tile0 all 4 halves + tile1 {Bh0, Bh1, Ah1}; A(1,0) from P1 of
  // iter 0. 14 ops; vmcnt(4) drains tile0 + B(1,0), leaves {B(1,1),A(1,1)}.
  stageA(0, 0); stageA(0, 1); stageB(0, 0); stageB(0, 1);
  stageB(1, 0); stageB(1, 1); stageA(1, 1);
  asm volatile("s_waitcnt vmcnt(4)" ::: "memory");
  __builtin_amdgcn_s_barrier();
  __builtin_amdgcn_sched_barrier(0);
  fill_af(afX, &As[0][0][0], wr, lane, 0);  // A0 ks0
  fill_bf(bf0, &Bs[0][0][0], wn, lane);     // B0 both ks

  for (int k = 0; k < KT; ++k) {
    const int buf = k & 1, nb = buf ^ 1;
    const u16* A0 = &As[buf][0][0];
    const u16* A1 = &As[buf][1][0];
    const u16* B1L = &Bs[buf][1][0];
    const u16* A0n = &As[nb][0][0];
    const u16* B0n = &Bs[nb][0][0];

    // ---- P1 (mq0,nq0) ----
    LGKM0();                                  // drains afX, bf0 (prev P4 fills)
    fill_af(afY, A0, wr, lane, 1);
    fill_bf(bf1, B1L, wn, lane);
    stageA(k + 1, 0);
    MFMA8(0, 0, 0, afX, bf0);
    LGKM0();                                  // afY, bf1
    fill_af(afX, A1, wr, lane, 0);            // for P2h0
    MFMA8(0, 0, 1, afY, bf0);
    __builtin_amdgcn_s_barrier();

    // ---- P2 (mq1,nq0) ----
    LGKM0();                                  // afX
    fill_af(afY, A1, wr, lane, 1);
    stageB(k + 2, 0);
    MFMA8(1, 0, 0, afX, bf0);
    LGKM0();                                  // afY
    fill_af(afX, A1, wr, lane, 0);            // re-read for P3h0
    MFMA8(1, 0, 1, afY, bf0);
    __builtin_amdgcn_s_barrier();

    // ---- P3 (mq1,nq1) ----
    LGKM0();                                  // afX
    fill_af(afY, A1, wr, lane, 1);            // re-read
    stageB(k + 2, 1);
    MFMA8(1, 1, 0, afX, bf1);
    LGKM0();                                  // afY
    fill_af(afX, A0, wr, lane, 0);            // re-read for P4h0
    MFMA8(1, 1, 1, afY, bf1);
    __builtin_amdgcn_s_barrier();

    // ---- P4 (mq0,nq1) ----
    LGKM0();                                  // afX
    fill_af(afY, A0, wr, lane, 1);            // re-read
    MFMA8(0, 1, 0, afX, bf1);
    LGKM0();                                  // afY
    stageA(k + 2, 1);
    if (k >= KT - 3) asm volatile("s_waitcnt vmcnt(0)" ::: "memory");
    else             asm volatile("s_waitcnt vmcnt(4)" ::: "memory");
    __builtin_amdgcn_s_barrier();             // all waves' tile-(k+1) loads landed
    __builtin_amdgcn_sched_barrier(0);
    if (k + 1 < KT) {                         // buf-crossing fills, hidden under h1
      fill_af(afX, A0n, wr, lane, 0);
      fill_bf(bf0, B0n, wn, lane);
    }
    MFMA8(0, 1, 1, afY, bf1);
    __builtin_amdgcn_s_barrier();             // phase boundary (protects P1 stage)
  }

  // ---- epilogue (optional fused RoPE for Q/K projections) ----
#pragma unroll
  for (int mi = 0; mi < 8; ++mi) {
    const int mq = mi >> 2, m = mi & 3;
#pragma unroll
    for (int ni = 0; ni < 4; ++ni) {
      const int nq = ni >> 1, n = ni & 1;
#pragma unroll
      for (int r = 0; r < 4; ++r) {
        size_t row = arow0 + mq * 128 + wr * 64 + m * 16 + ((lane >> 4) << 2) + r;
        size_t col = (size_t)tc * 256 + nq * 128 + wn * 32 + n * 16 + (lane & 15);
        float v = acc[mi][ni][r];
        if constexpr (ROPE) {
          float o = __shfl_xor(v, 1);                       // partner (col^1), same row
          int s = (int)(row & (S_ - 1));
          int p = (wn * 32 + n * 16 + (lane & 14)) >> 1;    // (col&127)>>1
          float cv = fc[(s << 6) + p];
          float sv = fs[(s << 6) + p];
          v = (lane & 1) ? (v * cv + o * sv) : (v * cv - o * sv);
        }
        if constexpr (__is_same(OutT, float)) {
          C[row * N + col] = v;
        } else {
          C[row * N + col] = f2bf(v);
        }
      }
    }
  }
}

// ---------------- Flash attention v4 (causal), swapped-operand 32x32 MFMA ----------------
// 512 threads = 8 waves, 256 q-rows per block (staging cost per MFMA halved vs v3b),
// 512 blocks = 2/CU resident in one round (16 waves/CU). K staged via gl_lds;
// V transposed via paired ds_write_b32 (kv pairs adjacent in Vt[d][kv]); lane map
// r0=lane>>1, dc=2w+(lane&1) gives 32-bank / 2-lane writes (free). Softmax fully
// in-register (lane owns one q row); defer-max (T13).
__global__ __launch_bounds__(512, 2) void attn_kernel(const u16* __restrict__ Q,
                                                      const u16* __restrict__ K,
                                                      const u16* __restrict__ V,
                                                      u16* __restrict__ O) {
  __shared__ u16 Ks[2][64 * 128];   // [kv][d], chunk-XOR swizzled (cc ^= row&7)
  __shared__ u16 Vt[2][128 * 64];   // [d][kv], chunk-XOR swizzled (kvchunk ^= d&7)

  const int blk = blockIdx.x;
  const int qt = 7 - (blk >> 6);    // longest-running q-tiles launch first
  const int bh = blk & 63;
  const int b = bh >> 5, h = bh & 31;
  const int q0 = qt << 8;           // 256 q-rows per block
  const int tid = threadIdx.x, lane = tid & 63, w = tid >> 6;
  const int wq0 = q0 + w * 32;
  const int l31 = lane & 31;
  const int hi = lane >> 5;               // 0/1 k-half
  const int qg = wq0 + l31;               // this lane's q row

  // V staging assignment: kv rows (2r0, 2r0+1), d-chunk dc
  const int r0 = lane >> 1;               // 0..31
  const int dc = 2 * w + (lane & 1);      // 0..15
  const int vd0 = dc * 8;

  bf16x8 qf[8];
#pragma unroll
  for (int kb = 0; kb < 8; ++kb)
    qf[kb] = *reinterpret_cast<const bf16x8*>(Q + (size_t)(b * S_ + qg) * D_ + h * HD_ + kb * 16 + hi * 8);

  f32x16 oacc[4] = {};   // O^T[dblock]: col=q(lane), row=d
  float mrun = -__builtin_inff(), lrun = 0.f;

  const int ntiles = 4 * qt + 4;
  u16x8 vr0, vr1;

  {
#pragma unroll
    for (int it = 0; it < 2; ++it) {
      int ff = it * 512 + tid;
      int row = ff >> 4, cc = ff & 15;
      int scc = cc ^ (row & 7);
      GLD_TO_LDS16(K + (size_t)(b * S_ + row) * D_ + h * HD_ + scc * 8, &Ks[0][ff << 3]);
    }
    vr0 = *reinterpret_cast<const u16x8*>(V + (size_t)(b * S_ + 2 * r0) * D_ + h * HD_ + vd0);
    vr1 = *reinterpret_cast<const u16x8*>(V + (size_t)(b * S_ + 2 * r0 + 1) * D_ + h * HD_ + vd0);
    u32* vt32 = reinterpret_cast<u32*>(&Vt[0][0]);
#pragma unroll
    for (int j = 0; j < 8; ++j) {
      int d = vd0 + j;
      u32 val = (u32)vr0[j] | ((u32)vr1[j] << 16);
      vt32[d * 32 + ((r0 >> 2) ^ j) * 4 + (r0 & 3)] = val;
    }
  }
  __syncthreads();

  for (int t = 0; t < ntiles; ++t) {
    const int cur = t & 1, nxt = cur ^ 1;
    const bool pre = (t + 1 < ntiles);
    if (pre) {
      const int kv1 = (t + 1) << 6;
#pragma unroll
      for (int it = 0; it < 2; ++it) {
        int ff = it * 512 + tid;
        int row = ff >> 4, cc = ff & 15;
        int scc = cc ^ (row & 7);
        GLD_TO_LDS16(K + (size_t)(b * S_ + kv1 + row) * D_ + h * HD_ + scc * 8, &Ks[nxt][ff << 3]);
      }
      vr0 = *reinterpret_cast<const u16x8*>(V + (size_t)(b * S_ + kv1 + 2 * r0) * D_ + h * HD_ + vd0);
      vr1 = *reinterpret_cast<const u16x8*>(V + (size_t)(b * S_ + kv1 + 2 * r0 + 1) * D_ + h * HD_ + vd0);
    }

    const int kv0 = t << 6;
    if (kv0 <= wq0 + 31) {  // wave-uniform causal skip
      f32x16 st[2] = {};
      __builtin_amdgcn_s_setprio(1);
#pragma unroll
      for (int kvh = 0; kvh < 2; ++kvh) {
#pragma unroll
        for (int kb = 0; kb < 8; ++kb) {
          int row = kvh * 32 + l31;
          int cc = (2 * kb + hi) ^ (row & 7);
          bf16x8 kf = *reinterpret_cast<const bf16x8*>(&Ks[cur][(row << 7) + (cc << 3)]);
          st[kvh] = __builtin_amdgcn_mfma_f32_32x32x16_bf16(kf, qf[kb], st[kvh], 0, 0, 0);
        }
      }
      __builtin_amdgcn_s_setprio(0);

      if (kv0 + 63 > wq0) {
#pragma unroll
        for (int kvh = 0; kvh < 2; ++kvh)
#pragma unroll
          for (int r = 0; r < 16; ++r) {
            int kvg = kv0 + kvh * 32 + (r & 3) + 8 * (r >> 2) + 4 * hi;
            if (kvg > qg) st[kvh][r] = -1e30f;
          }
      }

      float vmax = -1e30f;
#pragma unroll
      for (int kvh = 0; kvh < 2; ++kvh)
#pragma unroll
        for (int r = 0; r < 16; ++r) vmax = fmaxf(vmax, st[kvh][r]);
      vmax = fmaxf(vmax, __shfl_xor(vmax, 32));
      // defer-max: rescale only when some row's max grew by >64 raw (~5.66 scaled)
      if (!__all(vmax <= mrun + 64.0f)) {
        float mnew = fmaxf(mrun, vmax);
        float sc = exp2f((mrun - mnew) * C2_);
        mrun = mnew;
        lrun *= sc;
#pragma unroll
        for (int db = 0; db < 4; ++db)
#pragma unroll
          for (int r = 0; r < 16; ++r) oacc[db][r] *= sc;
      }
      float psum = 0.f;
#pragma unroll
      for (int kvh = 0; kvh < 2; ++kvh)
#pragma unroll
        for (int r = 0; r < 16; ++r) {
          float p = exp2f((st[kvh][r] - mrun) * C2_);
          st[kvh][r] = p;
          psum += p;
        }
      psum += __shfl_xor(psum, 32);
      lrun += psum;

      __builtin_amdgcn_s_setprio(1);
#pragma unroll
      for (int h2 = 0; h2 < 2; ++h2)
#pragma unroll
        for (int s2 = 0; s2 < 2; ++s2) {
          const int rb = s2 * 8;
          u32 w0, w1, w2, w3;
          asm("v_cvt_pk_bf16_f32 %0, %1, %2" : "=v"(w0) : "v"(st[h2][rb + 0]), "v"(st[h2][rb + 1]));
          asm("v_cvt_pk_bf16_f32 %0, %1, %2" : "=v"(w1) : "v"(st[h2][rb + 2]), "v"(st[h2][rb + 3]));
          asm("v_cvt_pk_bf16_f32 %0, %1, %2" : "=v"(w2) : "v"(st[h2][rb + 4]), "v"(st[h2][rb + 5]));
          asm("v_cvt_pk_bf16_f32 %0, %1, %2" : "=v"(w3) : "v"(st[h2][rb + 6]), "v"(st[h2][rb + 7]));
          u32 sw0 = (u32)__shfl_xor((int)w0, 32);
          u32 sw1 = (u32)__shfl_xor((int)w1, 32);
          u32 sw2 = (u32)__shfl_xor((int)w2, 32);
          u32 sw3 = (u32)__shfl_xor((int)w3, 32);
          u32x4 fw;
          fw[0] = hi ? sw2 : w0;
          fw[1] = hi ? sw3 : w1;
          fw[2] = hi ? w2 : sw0;
          fw[3] = hi ? w3 : sw1;
          bf16x8 pfrag = __builtin_bit_cast(bf16x8, fw);
#pragma unroll
          for (int db = 0; db < 4; ++db) {
            int d = db * 32 + l31;
            int cc = (h2 * 4 + s2 * 2 + hi) ^ (d & 7);
            bf16x8 va = *reinterpret_cast<const bf16x8*>(&Vt[cur][(d << 6) + (cc << 3)]);
            oacc[db] = __builtin_amdgcn_mfma_f32_32x32x16_bf16(va, pfrag, oacc[db], 0, 0, 0);
          }
        }
      __builtin_amdgcn_s_setprio(0);
    }

    if (pre) {
      u32* vt32 = reinterpret_cast<u32*>(&Vt[nxt][0]);
#pragma unroll
      for (int j = 0; j < 8; ++j) {
        int d = vd0 + j;
        u32 val = (u32)vr0[j] | ((u32)vr1[j] << 16);
        vt32[d * 32 + ((r0 >> 2) ^ j) * 4 + (r0 & 3)] = val;
      }
    }
    __syncthreads();
  }

  const float rinv = 1.0f / lrun;
#pragma unroll
  for (int db = 0; db < 4; ++db)
#pragma unroll
    for (int g = 0; g < 4; ++g) {
      u16x4 o4;
#pragma unroll
      for (int j = 0; j < 4; ++j) o4[j] = f2bf(oacc[db][g * 4 + j] * rinv);
      int d = db * 32 + g * 8 + 4 * hi;
      *reinterpret_cast<u16x4*>(O + (size_t)(b * S_ + qg) * D_ + h * HD_ + d) = o4;
    }
}

// ---------------- launcher ----------------
extern "C" void kernel_launch(void* const* d_in, const int* in_sizes, int n_in,
                              void* d_out, int out_size, void* d_ws, size_t ws_size,
                              hipStream_t stream) {
  const float* x = (const float*)d_in[0];
  const float* wq = (const float*)d_in[1];
  const float* wk = (const float*)d_in[2];
  const float* wv = (const float*)d_in[3];
  const float* wo = (const float*)d_in[4];
  const float* fc = (const float*)d_in[5];
  const float* fs = (const float*)d_in[6];
  float* out = (float*)d_out;

  const size_t SLOT = (size_t)B_ * S_ * D_;  // 16,777,216 elements
  u16* ws = (u16*)d_ws;
  u16* wqb = ws + 0 * SLOT;
  u16* wkb = ws + 1 * SLOT;
  u16* wvb = ws + 2 * SLOT;
  u16* wob = ws + 3 * SLOT;
  u16* xb  = ws + 4 * SLOT;  // reused as attention output O after QKV GEMMs
  u16* Qb  = ws + 5 * SLOT;
  u16* Kb  = ws + 6 * SLOT;
  u16* Vb  = ws + 7 * SLOT;
  u16* Ob  = xb;

  const int n4 = (int)(SLOT / 4);
  cvt5_kernel<<<2560, 256, 0, stream>>>(x, wq, wk, wv, wo, xb, wqb, wkb, wvb, wob, n4);

  gemm256_kernel<u16, true><<<256, 512, 0, stream>>>(xb, wqb, Qb, B_ * S_, D_, D_, fc, fs);
  gemm256_kernel<u16, true><<<256, 512, 0, stream>>>(xb, wkb, Kb, B_ * S_, D_, D_, fc, fs);
  gemm256_kernel<u16, false><<<256, 512, 0, stream>>>(xb, wvb, Vb, B_ * S_, D_, D_, fc, fs);

  attn_kernel<<<512, 512, 0, stream>>>(Qb, Kb, Vb, Ob);

  gemm256_kernel<float, false><<<256, 512, 0, stream>>>(Ob, wob, out, B_ * S_, D_, D_, fc, fs);
}